// Round 20
// baseline (347.706 us; speedup 1.0000x reference)
//
#include <hip/hip_runtime.h>
#include <cstdint>
#include <cstddef>

typedef __bf16 bf16x8 __attribute__((ext_vector_type(8)));
typedef float f32x4 __attribute__((ext_vector_type(4)));
typedef float f32x16 __attribute__((ext_vector_type(16)));
typedef unsigned short u16;
typedef unsigned uint2v __attribute__((ext_vector_type(2)));

namespace {
constexpr int Bb = 4, Tt = 2048, Cc = 1024, Hh = 16, Dd = 64;
constexpr int ROWS = Bb * Tt;   // 8192
constexpr int C3 = 3 * Cc;      // 3072
constexpr float LNEPS = 1e-5f;
constexpr float SCL2 = 0.18033688011112042f; // 0.125 * log2(e)
}

__device__ __forceinline__ u16 f2bf(float f) {
  union { float f; unsigned u; } v; v.f = f;
  return (u16)((v.u + 0x7fffu + ((v.u >> 16) & 1u)) >> 16);
}
__device__ __forceinline__ u16 bfn(float f) {
  union { __bf16 b; u16 u; } t; t.b = (__bf16)f; return t.u;
}
__device__ __forceinline__ unsigned pk2(float lo, float hi) {
  union { __bf16 b[2]; unsigned u; } t;
  t.b[0] = (__bf16)lo; t.b[1] = (__bf16)hi;
  return t.u;
}
__device__ __forceinline__ float exp2_hw(float x) {
  float r;
  asm("v_exp_f32 %0, %1" : "=v"(r) : "v"(x));
  return r;
}
__device__ __forceinline__ uint2v plswap(unsigned a, unsigned b) {
  return __builtin_amdgcn_permlane32_swap(a, b, false, false);
}
__device__ __forceinline__ float xhalf_max(float x) {
  union { float f; unsigned u; } c; c.f = x;
  uint2v r = plswap(c.u, c.u);
  union { unsigned u; float f; } a, b; a.u = r[0]; b.u = r[1];
  return fmaxf(a.f, b.f);
}
__device__ __forceinline__ float xhalf_sum(float x) {
  union { float f; unsigned u; } c; c.f = x;
  uint2v r = plswap(c.u, c.u);
  union { unsigned u; float f; } a, b; a.u = r[0]; b.u = r[1];
  return a.f + b.f;
}

typedef __attribute__((address_space(3))) unsigned lds_u32;
typedef __attribute__((address_space(1))) const unsigned glb_u32;
__device__ __forceinline__ void gload_lds16(const u16* g, u16* l) {
  __builtin_amdgcn_global_load_lds((glb_u32*)g, (lds_u32*)l, 16, 0, 0);
}

// ---------------- LayerNorm: one wave per row (no LDS, no block barrier) ----------------
__global__ __launch_bounds__(256) void ln_kernel(
    const float* __restrict__ x, const float* __restrict__ g,
    const float* __restrict__ b, u16* __restrict__ out)
{
  const int row = blockIdx.x * 4 + (threadIdx.x >> 6);
  const int l   = threadIdx.x & 63;
  const float4* xr = reinterpret_cast<const float4*>(x + (size_t)row * Cc);
  float4 v[4];
  float s = 0.f, ss = 0.f;
#pragma unroll
  for (int i = 0; i < 4; i++) {
    v[i] = xr[l + i * 64];
    s  += v[i].x + v[i].y + v[i].z + v[i].w;
    ss += v[i].x * v[i].x + v[i].y * v[i].y + v[i].z * v[i].z + v[i].w * v[i].w;
  }
#pragma unroll
  for (int off = 1; off < 64; off <<= 1) {
    s  += __shfl_xor(s, off);
    ss += __shfl_xor(ss, off);
  }
  const float mu   = s * (1.0f / Cc);
  const float var  = ss * (1.0f / Cc) - mu * mu;
  const float rstd = rsqrtf(var + LNEPS);
  const float4* gp = reinterpret_cast<const float4*>(g);
  const float4* bp = reinterpret_cast<const float4*>(b);
  ushort4* op = reinterpret_cast<ushort4*>(out + (size_t)row * Cc);
#pragma unroll
  for (int i = 0; i < 4; i++) {
    const float4 gv = gp[l + i * 64];
    const float4 bv = bp[l + i * 64];
    ushort4 o;
    o.x = f2bf((v[i].x - mu) * rstd * gv.x + bv.x);
    o.y = f2bf((v[i].y - mu) * rstd * gv.y + bv.y);
    o.z = f2bf((v[i].z - mu) * rstd * gv.z + bv.z);
    o.w = f2bf((v[i].w - mu) * rstd * gv.w + bv.w);
    op[l + i * 64] = o;
  }
}

// ---------------- merged weight transpose+cast: 4 matrices, one launch ----------------
__global__ __launch_bounds__(256) void wcast_all(
    const float* __restrict__ w0, u16* __restrict__ o0,   // 1024x3072
    const float* __restrict__ w1, u16* __restrict__ o1,   // 1024x1024
    const float* __restrict__ w2, u16* __restrict__ o2,   // 1024x4096
    const float* __restrict__ w3, u16* __restrict__ o3)   // 4096x1024
{
  int bi = blockIdx.x;
  const float* w; u16* wt; int K, N, nbx;
  if (bi < 3072)      { w = w0; wt = o0; K = 1024; N = 3072; nbx = 96; }
  else if (bi < 4096) { bi -= 3072; w = w1; wt = o1; K = 1024; N = 1024; nbx = 32; }
  else if (bi < 8192) { bi -= 4096; w = w2; wt = o2; K = 1024; N = 4096; nbx = 128; }
  else                { bi -= 8192; w = w3; wt = o3; K = 4096; N = 1024; nbx = 32; }
  const int n0 = (bi % nbx) * 32, k0 = (bi / nbx) * 32;

  __shared__ float tile[32][33];
  const int tx = threadIdx.x & 31, ty = threadIdx.x >> 5; // 32x8
#pragma unroll
  for (int i = 0; i < 4; i++)
    tile[ty + i * 8][tx] = w[(size_t)(k0 + ty + i * 8) * N + n0 + tx];
  __syncthreads();
#pragma unroll
  for (int i = 0; i < 4; i++)
    wt[(size_t)(n0 + ty + i * 8) * K + k0 + tx] = f2bf(tile[tx][ty + i * 8]);
}

enum { EPI_BIAS_BF16 = 0, EPI_BIAS_RELU_BF16 = 1, EPI_BIAS_RES_F32 = 2 };

// ---------------- GEMM 256x256 8-phase counted-vmcnt (QKV / FC1) ----------------
template <int EPI, bool FVT>
__global__ __launch_bounds__(512, 1) void gemm8p(
    const u16* __restrict__ A, const u16* __restrict__ Bt,
    const float* __restrict__ bias, const float* __restrict__ res,
    void* __restrict__ outp, u16* __restrict__ vtout, int M, int N, int K)
{
  __shared__ alignas(16) u16 Asl[2][2][128 * 64];
  __shared__ alignas(16) u16 Bsl[2][2][128 * 64];

  const int tid = threadIdx.x;
  const int l   = tid & 63;
  const int wv  = tid >> 6;
  const int wr  = wv >> 2;
  const int wc  = wv & 3;
  const int lr  = l & 15;
  const int lg  = (l >> 4) & 3;

  const int xcd = (int)blockIdx.x & 7;
  const int j   = (int)blockIdx.x >> 3;
  const int nbn = N >> 8;
  const int bmpx = ((int)gridDim.x >> 3) / nbn;
  const int bm = (xcd * bmpx + j / nbn) << 8;
  const int bn = (j % nbn) << 8;

  const int srw = wv * 8 + (l >> 3);
  const int sch = ((l & 7) ^ ((l >> 3) & 7)) * 8;
  const int dst = (l & 7) * 8;

  const int csw0 = (lg ^ (lr & 7)) * 8;
  const int csw1 = ((4 + lg) ^ (lr & 7)) * 8;
  const int ar = wr * 64;
  const int br = wc * 32;

  f32x4 acc[8][4];
#pragma unroll
  for (int mi = 0; mi < 8; mi++)
#pragma unroll
    for (int nj = 0; nj < 4; nj++)
      acc[mi][nj] = (f32x4){0.f, 0.f, 0.f, 0.f};

  const int NT = K >> 6;

  auto stA = [&](int h, int tt) {
#pragma unroll
    for (int L = 0; L < 2; ++L)
      gload_lds16(A + (size_t)(bm + h * 128 + L * 64 + srw) * K + tt * 64 + sch,
                  &Asl[tt & 1][h][(L * 64 + srw) * 64 + dst]);
  };
  auto stB = [&](int h, int tt) {
#pragma unroll
    for (int L = 0; L < 2; ++L)
      gload_lds16(Bt + (size_t)(bn + h * 128 + L * 64 + srw) * K + tt * 64 + sch,
                  &Bsl[tt & 1][h][(L * 64 + srw) * 64 + dst]);
  };

  stA(0, 0); stB(0, 0); stB(1, 0); stA(1, 0);
  asm volatile("s_waitcnt vmcnt(4)" ::: "memory");
  asm volatile("s_barrier" ::: "memory");

  bf16x8 af[4][2], bfr[2][2][2];

  for (int t = 0; t < NT; ++t) {
    const int cb = t & 1;
    const bool st = (t + 1 < NT);
    const u16* Ah0 = &Asl[cb][0][0];
    const u16* Ah1 = &Asl[cb][1][0];
    const u16* Bh0 = &Bsl[cb][0][0];
    const u16* Bh1 = &Bsl[cb][1][0];

    // ---- P1 ----
#pragma unroll
    for (int m = 0; m < 4; ++m) {
      af[m][0] = *reinterpret_cast<const bf16x8*>(Ah0 + (ar + m * 16 + lr) * 64 + csw0);
      af[m][1] = *reinterpret_cast<const bf16x8*>(Ah0 + (ar + m * 16 + lr) * 64 + csw1);
    }
#pragma unroll
    for (int n = 0; n < 2; ++n) {
      bfr[0][n][0] = *reinterpret_cast<const bf16x8*>(Bh0 + (br + n * 16 + lr) * 64 + csw0);
      bfr[0][n][1] = *reinterpret_cast<const bf16x8*>(Bh0 + (br + n * 16 + lr) * 64 + csw1);
    }
    if (st) { stA(0, t + 1); stB(0, t + 1); }
    asm volatile("s_barrier" ::: "memory");
    __builtin_amdgcn_s_setprio(1);
#pragma unroll
    for (int m = 0; m < 4; ++m)
#pragma unroll
      for (int n = 0; n < 2; ++n) {
        acc[m][n] = __builtin_amdgcn_mfma_f32_16x16x32_bf16(af[m][0], bfr[0][n][0], acc[m][n], 0, 0, 0);
        acc[m][n] = __builtin_amdgcn_mfma_f32_16x16x32_bf16(af[m][1], bfr[0][n][1], acc[m][n], 0, 0, 0);
      }
    __builtin_amdgcn_s_setprio(0);
    if (st) asm volatile("s_waitcnt vmcnt(6)" ::: "memory");
    else    asm volatile("s_waitcnt vmcnt(2)" ::: "memory");
    asm volatile("s_barrier" ::: "memory");

    // ---- P2 ----
#pragma unroll
    for (int n = 0; n < 2; ++n) {
      bfr[1][n][0] = *reinterpret_cast<const bf16x8*>(Bh1 + (br + n * 16 + lr) * 64 + csw0);
      bfr[1][n][1] = *reinterpret_cast<const bf16x8*>(Bh1 + (br + n * 16 + lr) * 64 + csw1);
    }
    if (st) stB(1, t + 1);
    asm volatile("s_barrier" ::: "memory");
    __builtin_amdgcn_s_setprio(1);
#pragma unroll
    for (int m = 0; m < 4; ++m)
#pragma unroll
      for (int n = 0; n < 2; ++n) {
        acc[m][2 + n] = __builtin_amdgcn_mfma_f32_16x16x32_bf16(af[m][0], bfr[1][n][0], acc[m][2 + n], 0, 0, 0);
        acc[m][2 + n] = __builtin_amdgcn_mfma_f32_16x16x32_bf16(af[m][1], bfr[1][n][1], acc[m][2 + n], 0, 0, 0);
      }
    __builtin_amdgcn_s_setprio(0);
    if (st) asm volatile("s_waitcnt vmcnt(6)" ::: "memory");
    else    asm volatile("s_waitcnt vmcnt(0)" ::: "memory");
    asm volatile("s_barrier" ::: "memory");

    // ---- P3 ----
#pragma unroll
    for (int m = 0; m < 4; ++m) {
      af[m][0] = *reinterpret_cast<const bf16x8*>(Ah1 + (ar + m * 16 + lr) * 64 + csw0);
      af[m][1] = *reinterpret_cast<const bf16x8*>(Ah1 + (ar + m * 16 + lr) * 64 + csw1);
    }
    if (st) stA(1, t + 1);
    asm volatile("s_barrier" ::: "memory");
    __builtin_amdgcn_s_setprio(1);
#pragma unroll
    for (int m = 0; m < 4; ++m)
#pragma unroll
      for (int n = 0; n < 2; ++n) {
        acc[4 + m][n] = __builtin_amdgcn_mfma_f32_16x16x32_bf16(af[m][0], bfr[0][n][0], acc[4 + m][n], 0, 0, 0);
        acc[4 + m][n] = __builtin_amdgcn_mfma_f32_16x16x32_bf16(af[m][1], bfr[0][n][1], acc[4 + m][n], 0, 0, 0);
      }
    __builtin_amdgcn_s_setprio(0);
    asm volatile("s_barrier" ::: "memory");

    // ---- P4 ----
    __builtin_amdgcn_s_setprio(1);
#pragma unroll
    for (int m = 0; m < 4; ++m)
#pragma unroll
      for (int n = 0; n < 2; ++n) {
        acc[4 + m][2 + n] = __builtin_amdgcn_mfma_f32_16x16x32_bf16(af[m][0], bfr[1][n][0], acc[4 + m][2 + n], 0, 0, 0);
        acc[4 + m][2 + n] = __builtin_amdgcn_mfma_f32_16x16x32_bf16(af[m][1], bfr[1][n][1], acc[4 + m][2 + n], 0, 0, 0);
      }
    __builtin_amdgcn_s_setprio(0);
    if (st) asm volatile("s_waitcnt vmcnt(4)" ::: "memory");
    asm volatile("s_barrier" ::: "memory");
  }

  // epilogue
#pragma unroll
  for (int mi = 0; mi < 8; ++mi) {
    const int row0 = bm + (mi >> 2) * 128 + wr * 64 + (mi & 3) * 16 + lg * 4;
#pragma unroll
    for (int nj = 0; nj < 4; ++nj) {
      const int col = bn + (nj >> 1) * 128 + wc * 32 + (nj & 1) * 16 + lr;
      const float bv = bias[col];
      u16 ov[4];
#pragma unroll
      for (int r = 0; r < 4; ++r) {
        const int row = row0 + r;
        float v = acc[mi][nj][r] + bv;
        if constexpr (EPI == EPI_BIAS_RELU_BF16) v = fmaxf(v, 0.0f);
        if constexpr (EPI == EPI_BIAS_RES_F32) {
          float* out = (float*)outp;
          out[(size_t)row * N + col] = v + res[(size_t)row * N + col];
        } else {
          ov[r] = f2bf(v);
          ((u16*)outp)[(size_t)row * N + col] = ov[r];
        }
      }
      if constexpr (FVT) {
        if (col >= 2 * Cc) {   // V columns -> vt[b][h][d][t], t = row&2047
          const int bq = row0 >> 11;
          const int t0 = row0 & 2047;
          const int hh2 = (col - 2 * Cc) >> 6;
          const int dd2 = col & 63;
          union { u16 u[4]; ushort4 v4; } pkv;
          pkv.u[0] = ov[0]; pkv.u[1] = ov[1]; pkv.u[2] = ov[2]; pkv.u[3] = ov[3];
          *reinterpret_cast<ushort4*>(
              &vtout[((size_t)(bq * Hh + hh2) * Dd + dd2) * Tt + t0]) = pkv.v4;
        }
      }
    }
  }
}

// ---------------- GEMM 128x128 (proj / FC2): m97 + T2 swizzle + L2 remap ----------------
template <int EPI>
__global__ __launch_bounds__(256, 3) void gemm_bt2(
    const u16* __restrict__ A, const u16* __restrict__ Bt,
    const float* __restrict__ bias, const float* __restrict__ res,
    void* __restrict__ outp, int M, int N, int K)
{
  constexpr int BM = 128, BN = 128, BK = 64;
  __shared__ alignas(16) u16 As[BM][BK];
  __shared__ alignas(16) u16 Bs[BN][BK];
  const int tid  = threadIdx.x;
  const int lane = tid & 63;
  const int wv   = tid >> 6;
  const int wr   = wv >> 1, wc = wv & 1;
  const int lr   = lane & 15, lg = lane >> 4;

  const int xcd = (int)blockIdx.x & 7;
  const int j   = (int)blockIdx.x >> 3;
  const int nbn = N >> 7;
  const int bmpx = ((int)gridDim.x >> 3) / nbn;
  const int bm = (xcd * bmpx + j / nbn) << 7;
  const int bn = (j % nbn) << 7;

  f32x4 acc[4][4];
#pragma unroll
  for (int mi = 0; mi < 4; mi++)
#pragma unroll
    for (int nj = 0; nj < 4; nj++)
      acc[mi][nj] = (f32x4){0.f, 0.f, 0.f, 0.f};

  const int srow = tid >> 3;
  const int scol = ((tid & 7) ^ (srow & 7)) * 8;
  const u16* ga = &A [(size_t)(bm + srow) * K + scol];
  const u16* gb = &Bt[(size_t)(bn + srow) * K + scol];
  u16* as_dst = &As[0][0] + (size_t)tid * 8;
  u16* bs_dst = &Bs[0][0] + (size_t)tid * 8;

  for (int k0 = 0; k0 < K; k0 += BK) {
#pragma unroll
    for (int p = 0; p < 4; p++) {
      gload_lds16(ga + (size_t)p * 32 * K + k0, as_dst + p * 2048);
      gload_lds16(gb + (size_t)p * 32 * K + k0, bs_dst + p * 2048);
    }
    __syncthreads();
#pragma unroll
    for (int kk = 0; kk < BK; kk += 32) {
      const int cb = kk >> 3;
      const int csw = ((cb + lg) ^ (lr & 7)) * 8;
      bf16x8 af[4], bfr[4];
#pragma unroll
      for (int mi = 0; mi < 4; mi++)
        af[mi] = *reinterpret_cast<const bf16x8*>(&As[wr * 64 + mi * 16 + lr][0] + csw);
#pragma unroll
      for (int nj = 0; nj < 4; nj++)
        bfr[nj] = *reinterpret_cast<const bf16x8*>(&Bs[wc * 64 + nj * 16 + lr][0] + csw);
#pragma unroll
      for (int mi = 0; mi < 4; mi++)
#pragma unroll
        for (int nj = 0; nj < 4; nj++)
          acc[mi][nj] = __builtin_amdgcn_mfma_f32_16x16x32_bf16(af[mi], bfr[nj], acc[mi][nj], 0, 0, 0);
    }
    __syncthreads();
  }

#pragma unroll
  for (int mi = 0; mi < 4; mi++) {
#pragma unroll
    for (int nj = 0; nj < 4; nj++) {
      const int col = bn + wc * 64 + nj * 16 + lr;
      const float bv = bias[col];
#pragma unroll
      for (int r = 0; r < 4; r++) {
        const int row = bm + wr * 64 + mi * 16 + lg * 4 + r;
        float v = acc[mi][nj][r] + bv;
        if constexpr (EPI == EPI_BIAS_RELU_BF16) v = fmaxf(v, 0.0f);
        if constexpr (EPI == EPI_BIAS_RES_F32) {
          float* out = (float*)outp;
          out[(size_t)row * N + col] = v + res[(size_t)row * N + col];
        } else {
          ((u16*)outp)[(size_t)row * N + col] = f2bf(v);
        }
      }
    }
  }
}

// ---------------- flash attention: 64 q-rows/wave, dual-chain, SIMD-paired + T5 setprio ----------------
__global__ __launch_bounds__(512, 1) void flash_attn(
    const u16* __restrict__ qkv,   // [B][T][3C]
    const u16* __restrict__ vt,    // [B][H][D][T]
    u16* __restrict__ y)           // [B][T][C]
{
  const int tid = threadIdx.x, lane = tid & 63, wv = tid >> 6;
  const int l31 = lane & 31, hf = lane >> 5;

  const int bid = blockIdx.x;
  const int lid = (bid & 7) * 32 + (bid >> 3);
  const int bh = lid >> 2, pg = lid & 3;
  const int b = bh >> 4, h = bh & 15;
  const int sbase = pg * 4 + (wv & 3);
  const int s = (wv < 4) ? sbase : (31 - sbase);

  const u16* qbase = qkv + (size_t)b * Tt * C3 + h * Dd;
  const u16* kbase = qbase + Cc;
  const u16* vbase = vt + (size_t)bh * Dd * Tt;

  bool dmask[16];
#pragma unroll
  for (int r = 0; r < 16; r++)
    dmask[r] = ((r & 3) + 8 * (r >> 2) + 4 * hf) > l31;

  const int qa0 = s * 64;
  const int qb0 = qa0 + 32;
  const int ta = 2 * s;

  bf16x8 qfa[4], qfb[4];
#pragma unroll
  for (int kc = 0; kc < 4; kc++) {
    qfa[kc] = *reinterpret_cast<const bf16x8*>(
        &qbase[(size_t)(qa0 + l31) * C3 + kc * 16 + hf * 8]);
    qfb[kc] = *reinterpret_cast<const bf16x8*>(
        &qbase[(size_t)(qb0 + l31) * C3 + kc * 16 + hf * 8]);
  }

  f32x16 oa[2], ob[2];
#pragma unroll
  for (int i = 0; i < 16; i++) { oa[0][i] = 0.f; oa[1][i] = 0.f; ob[0][i] = 0.f; ob[1][i] = 0.f; }
  float mA = -INFINITY, lA = 0.0f, mB = -INFINITY, lB = 0.0f;

  const u16* kptr = &kbase[(size_t)l31 * C3 + hf * 8];
  const u16* vp0 = &vbase[(size_t)l31 * Tt + hf * 8];
  const u16* vp1 = vp0 + (size_t)32 * Tt;

  bf16x8 kf[4];
#pragma unroll
  for (int kc = 0; kc < 4; kc++)
    kf[kc] = *reinterpret_cast<const bf16x8*>(kptr + kc * 16);

  for (int kt = 0; kt <= ta; ++kt) {
    bf16x8 vf[2][2];
#pragma unroll
    for (int ch = 0; ch < 2; ch++) {
      vf[0][ch] = *reinterpret_cast<const bf16x8*>(vp0 + ch * 16);
      vf[1][ch] = *reinterpret_cast<const bf16x8*>(vp1 + ch * 16);
    }
    vp0 += 32; vp1 += 32;

    f32x16 sA, sB;
#pragma unroll
    for (int i = 0; i < 16; i++) { sA[i] = 0.f; sB[i] = 0.f; }
    __builtin_amdgcn_s_setprio(1);   // T5: QK^T cluster
#pragma unroll
    for (int kc = 0; kc < 4; kc++) {
      sA = __builtin_amdgcn_mfma_f32_32x32x16_bf16(kf[kc], qfa[kc], sA, 0, 0, 0);
      sB = __builtin_amdgcn_mfma_f32_32x32x16_bf16(kf[kc], qfb[kc], sB, 0, 0, 0);
    }
    __builtin_amdgcn_s_setprio(0);

    kptr += (size_t)32 * C3;
    bf16x8 kn[4];
#pragma unroll
    for (int kc = 0; kc < 4; kc++)
      kn[kc] = *reinterpret_cast<const bf16x8*>(kptr + kc * 16);

    const bool diagA = (kt == ta);

    float svA[16], svB[16];
#pragma unroll
    for (int r = 0; r < 16; r++) {
      svA[r] = sA[r];
      if (diagA && dmask[r]) svA[r] = -INFINITY;
      svB[r] = sB[r];
    }

    float mAa = fmaxf(fmaxf(svA[0], svA[1]), fmaxf(svA[2], svA[3]));
    float mAb = fmaxf(fmaxf(svA[4], svA[5]), fmaxf(svA[6], svA[7]));
    float mAc = fmaxf(fmaxf(svA[8], svA[9]), fmaxf(svA[10], svA[11]));
    float mAd = fmaxf(fmaxf(svA[12], svA[13]), fmaxf(svA[14], svA[15]));
    float m8A = fmaxf(fmaxf(mAa, mAb), fmaxf(mAc, mAd));
    float mBa = fmaxf(fmaxf(svB[0], svB[1]), fmaxf(svB[2], svB[3]));
    float mBb = fmaxf(fmaxf(svB[4], svB[5]), fmaxf(svB[6], svB[7]));
    float mBc = fmaxf(fmaxf(svB[8], svB[9]), fmaxf(svB[10], svB[11]));
    float mBd = fmaxf(fmaxf(svB[12], svB[13]), fmaxf(svB[14], svB[15]));
    float m8B = fmaxf(fmaxf(mBa, mBb), fmaxf(mBc, mBd));
    m8A = xhalf_max(m8A);
    m8B = xhalf_max(m8B);

    if (!__all(m8A - mA <= 64.0f)) {
      const float mnew  = fmaxf(mA, m8A);
      const float alpha = exp2_hw((mA - mnew) * SCL2);
      lA *= alpha;
#pragma unroll
      for (int i = 0; i < 16; i++) { oa[0][i] *= alpha; oa[1][i] *= alpha; }
      mA = mnew;
    }
    if (!__all(m8B - mB <= 64.0f)) {
      const float mnew  = fmaxf(mB, m8B);
      const float alpha = exp2_hw((mB - mnew) * SCL2);
      lB *= alpha;
#pragma unroll
      for (int i = 0; i < 16; i++) { ob[0][i] *= alpha; ob[1][i] *= alpha; }
      mB = mnew;
    }

    const float msA = mA * SCL2;
    const float msB = mB * SCL2;
    float pA[16], pB[16];
#pragma unroll
    for (int r = 0; r < 16; r++) {
      pA[r] = exp2_hw(fmaf(svA[r], SCL2, -msA));
      pB[r] = exp2_hw(fmaf(svB[r], SCL2, -msB));
    }
    {
      float a0 = ((pA[0] + pA[1]) + (pA[2] + pA[3])) + ((pA[4] + pA[5]) + (pA[6] + pA[7]));
      float a1 = ((pA[8] + pA[9]) + (pA[10] + pA[11])) + ((pA[12] + pA[13]) + (pA[14] + pA[15]));
      lA += a0 + a1;
      float b0 = ((pB[0] + pB[1]) + (pB[2] + pB[3])) + ((pB[4] + pB[5]) + (pB[6] + pB[7]));
      float b1 = ((pB[8] + pB[9]) + (pB[10] + pB[11])) + ((pB[12] + pB[13]) + (pB[14] + pB[15]));
      lB += b0 + b1;
    }

    unsigned pwA[2][4], pwB[2][4];
#pragma unroll
    for (int ch = 0; ch < 2; ch++) {
      const int bs = ch * 8;
      {
        unsigned w0 = pk2(pA[bs + 0], pA[bs + 1]);
        unsigned w1 = pk2(pA[bs + 2], pA[bs + 3]);
        unsigned w2 = pk2(pA[bs + 4], pA[bs + 5]);
        unsigned w3 = pk2(pA[bs + 6], pA[bs + 7]);
        uint2v r02 = plswap(w0, w2);
        uint2v r13 = plswap(w1, w3);
        pwA[ch][0] = r02[0]; pwA[ch][2] = r02[1];
        pwA[ch][1] = r13[0]; pwA[ch][3] = r13[1];
      }
      {
        unsigned w0 = pk2(pB[bs + 0], pB[bs + 1]);
        unsigned w1 = pk2(pB[bs + 2], pB[bs + 3]);
        unsigned w2 = pk2(pB[bs + 4], pB[bs + 5]);
        unsigned w3 = pk2(pB[bs + 6], pB[bs + 7]);
        uint2v r02 = plswap(w0, w2);
        uint2v r13 = plswap(w1, w3);
        pwB[ch][0] = r02[0]; pwB[ch][2] = r02[1];
        pwB[ch][1] = r13[0]; pwB[ch][3] = r13[1];
      }
    }

    __builtin_amdgcn_s_setprio(1);   // T5: PV cluster
#pragma unroll
    for (int d0i = 0; d0i < 2; d0i++)
#pragma unroll
      for (int ch = 0; ch < 2; ch++) {
        union { unsigned w[4]; bf16x8 v; } pa, pb;
        pa.w[0] = pwA[ch][0]; pa.w[1] = pwA[ch][1];
        pa.w[2] = pwA[ch][2]; pa.w[3] = pwA[ch][3];
        pb.w[0] = pwB[ch][0]; pb.w[1] = pwB[ch][1];
        pb.w[2] = pwB[ch][2]; pb.w[3] = pwB[ch][3];
        oa[d0i] = __builtin_amdgcn_mfma_f32_32x32x16_bf16(vf[d0i][ch], pa.v, oa[d0i], 0, 0, 0);
        ob[d0i] = __builtin_amdgcn_mfma_f32_32x32x16_bf16(vf[d0i][ch], pb.v, ob[d0i], 0, 0, 0);
      }
    __builtin_amdgcn_s_setprio(0);

#pragma unroll
    for (int kc = 0; kc < 4; kc++) kf[kc] = kn[kc];
  }

  // peeled tile: group B only, diagonal-masked
  {
    bf16x8 vf[2][2];
#pragma unroll
    for (int ch = 0; ch < 2; ch++) {
      vf[0][ch] = *reinterpret_cast<const bf16x8*>(vp0 + ch * 16);
      vf[1][ch] = *reinterpret_cast<const bf16x8*>(vp1 + ch * 16);
    }

    f32x16 sB;
#pragma unroll
    for (int i = 0; i < 16; i++) sB[i] = 0.f;
    __builtin_amdgcn_s_setprio(1);
#pragma unroll
    for (int kc = 0; kc < 4; kc++)
      sB = __builtin_amdgcn_mfma_f32_32x32x16_bf16(kf[kc], qfb[kc], sB, 0, 0, 0);
    __builtin_amdgcn_s_setprio(0);

    float svB[16];
#pragma unroll
    for (int r = 0; r < 16; r++) {
      svB[r] = sB[r];
      if (dmask[r]) svB[r] = -INFINITY;
    }
    float mBa = fmaxf(fmaxf(svB[0], svB[1]), fmaxf(svB[2], svB[3]));
    float mBb = fmaxf(fmaxf(svB[4], svB[5]), fmaxf(svB[6], svB[7]));
    float mBc = fmaxf(fmaxf(svB[8], svB[9]), fmaxf(svB[10], svB[11]));
    float mBd = fmaxf(fmaxf(svB[12], svB[13]), fmaxf(svB[14], svB[15]));
    float m8B = fmaxf(fmaxf(mBa, mBb), fmaxf(mBc, mBd));
    m8B = xhalf_max(m8B);

    if (!__all(m8B - mB <= 64.0f)) {
      const float mnew  = fmaxf(mB, m8B);
      const float alpha = exp2_hw((mB - mnew) * SCL2);
      lB *= alpha;
#pragma unroll
      for (int i = 0; i < 16; i++) { ob[0][i] *= alpha; ob[1][i] *= alpha; }
      mB = mnew;
    }
    const float msB = mB * SCL2;
    float pB[16];
#pragma unroll
    for (int r = 0; r < 16; r++)
      pB[r] = exp2_hw(fmaf(svB[r], SCL2, -msB));
    {
      float b0 = ((pB[0] + pB[1]) + (pB[2] + pB[3])) + ((pB[4] + pB[5]) + (pB[6] + pB[7]));
      float b1 = ((pB[8] + pB[9]) + (pB[10] + pB[11])) + ((pB[12] + pB[13]) + (pB[14] + pB[15]));
      lB += b0 + b1;
    }
    unsigned pwB[2][4];
#pragma unroll
    for (int ch = 0; ch < 2; ch++) {
      const int bs = ch * 8;
      unsigned w0 = pk2(pB[bs + 0], pB[bs + 1]);
      unsigned w1 = pk2(pB[bs + 2], pB[bs + 3]);
      unsigned w2 = pk2(pB[bs + 4], pB[bs + 5]);
      unsigned w3 = pk2(pB[bs + 6], pB[bs + 7]);
      uint2v r02 = plswap(w0, w2);
      uint2v r13 = plswap(w1, w3);
      pwB[ch][0] = r02[0]; pwB[ch][2] = r02[1];
      pwB[ch][1] = r13[0]; pwB[ch][3] = r13[1];
    }
    __builtin_amdgcn_s_setprio(1);
#pragma unroll
    for (int d0i = 0; d0i < 2; d0i++)
#pragma unroll
      for (int ch = 0; ch < 2; ch++) {
        union { unsigned w[4]; bf16x8 v; } pb;
        pb.w[0] = pwB[ch][0]; pb.w[1] = pwB[ch][1];
        pb.w[2] = pwB[ch][2]; pb.w[3] = pwB[ch][3];
        ob[d0i] = __builtin_amdgcn_mfma_f32_32x32x16_bf16(vf[d0i][ch], pb.v, ob[d0i], 0, 0, 0);
      }
    __builtin_amdgcn_s_setprio(0);
  }

  {
    const float lsA = xhalf_sum(lA);
    const float invA = 1.0f / lsA;
    u16* yrow = y + (size_t)(b * Tt + qa0 + l31) * Cc + h * Dd;
#pragma unroll
    for (int d0i = 0; d0i < 2; d0i++)
#pragma unroll
      for (int qd = 0; qd < 4; qd++) {
        ushort4 o;
        o.x = bfn(oa[d0i][qd * 4 + 0] * invA);
        o.y = bfn(oa[d0i][qd * 4 + 1] * invA);
        o.z = bfn(oa[d0i][qd * 4 + 2] * invA);
        o.w = bfn(oa[d0i][qd * 4 + 3] * invA);
        *reinterpret_cast<ushort4*>(&yrow[d0i * 32 + qd * 8 + hf * 4]) = o;
      }
  }
  {
    const float lsB = xhalf_sum(lB);
    const float invB = 1.0f / lsB;
    u16* yrow = y + (size_t)(b * Tt + qb0 + l31) * Cc + h * Dd;
#pragma unroll
    for (int d0i = 0; d0i < 2; d0i++)
#pragma unroll
      for (int qd = 0; qd < 4; qd++) {
        ushort4 o;
        o.x = bfn(ob[d0i][qd * 4 + 0] * invB);
        o.y = bfn(ob[d0i][qd * 4 + 1] * invB);
        o.z = bfn(ob[d0i][qd * 4 + 2] * invB);
        o.w = bfn(ob[d0i][qd * 4 + 3] * invB);
        *reinterpret_cast<ushort4*>(&yrow[d0i * 32 + qd * 8 + hf * 4]) = o;
      }
  }
}

// ---------------- launch ----------------
extern "C" void kernel_launch(void* const* d_in, const int* in_sizes, int n_in,
                              void* d_out, int out_size, void* d_ws, size_t ws_size,
                              hipStream_t stream)
{
  const float* x      = (const float*)d_in[0];
  const float* ln1_g  = (const float*)d_in[1];
  const float* ln1_b  = (const float*)d_in[2];
  const float* attn_w = (const float*)d_in[3];
  const float* attn_b = (const float*)d_in[4];
  const float* proj_w = (const float*)d_in[5];
  const float* proj_b = (const float*)d_in[6];
  const float* ln2_g  = (const float*)d_in[7];
  const float* ln2_b  = (const float*)d_in[8];
  const float* fc1_w  = (const float*)d_in[9];
  const float* fc1_b  = (const float*)d_in[10];
  const float* fc2_w  = (const float*)d_in[11];
  const float* fc2_b  = (const float*)d_in[12];
  float* out = (float*)d_out;

  char* ws = (char*)d_ws;
  size_t o = 0;
  auto alloc = [&](size_t bytes) { char* p = ws + o; o += bytes; return p; };
  u16* wqkv_t  = (u16*)alloc((size_t)C3 * Cc * 2);
  u16* wproj_t = (u16*)alloc((size_t)Cc * Cc * 2);
  u16* wfc1_t  = (u16*)alloc((size_t)4096 * Cc * 2);
  u16* wfc2_t  = (u16*)alloc((size_t)Cc * 4096 * 2);
  u16* h_bf    = (u16*)alloc((size_t)ROWS * Cc * 2);
  u16* y_bf    = (u16*)alloc((size_t)ROWS * Cc * 2);
  u16* qkv_raw = (u16*)alloc((size_t)ROWS * C3 * 2);
  u16* vt      = (u16*)alloc((size_t)Bb * Hh * Dd * Tt * 2);
  u16* hh      = qkv_raw; // aliases qkv_raw+vt, both dead by FC1 time

  wcast_all<<<12288, 256, 0, stream>>>(attn_w, wqkv_t, proj_w, wproj_t,
                                       fc1_w, wfc1_t, fc2_w, wfc2_t);

  ln_kernel<<<ROWS / 4, 256, 0, stream>>>(x, ln1_g, ln1_b, h_bf);
  gemm8p<EPI_BIAS_BF16, true><<<8 * (ROWS / 256 / 8) * (C3 / 256), 512, 0, stream>>>(
      h_bf, wqkv_t, attn_b, nullptr, qkv_raw, vt, ROWS, C3, Cc);
  flash_attn<<<dim3(256), 512, 0, stream>>>(qkv_raw, vt, y_bf);
  gemm_bt2<EPI_BIAS_RES_F32><<<64 * (Cc / 128), 256, 0, stream>>>(
      y_bf, wproj_t, proj_b, x, out, ROWS, Cc, Cc);
  ln_kernel<<<ROWS / 4, 256, 0, stream>>>(out, ln2_g, ln2_b, h_bf);
  gemm8p<EPI_BIAS_RELU_BF16, false><<<8 * (ROWS / 256 / 8) * (4096 / 256), 512, 0, stream>>>(
      h_bf, wfc1_t, fc1_b, nullptr, hh, nullptr, ROWS, 4096, Cc);
  gemm_bt2<EPI_BIAS_RES_F32><<<64 * (Cc / 128), 256, 0, stream>>>(
      hh, wfc2_t, fc2_b, out, out, ROWS, Cc, 4096);
}

// Round 21
// 347.253 us; speedup vs baseline: 1.0013x; 1.0013x over previous
//
#include <hip/hip_runtime.h>
#include <cstdint>
#include <cstddef>

typedef __bf16 bf16x8 __attribute__((ext_vector_type(8)));
typedef float f32x4 __attribute__((ext_vector_type(4)));
typedef float f32x16 __attribute__((ext_vector_type(16)));
typedef unsigned short u16;
typedef unsigned uint2v __attribute__((ext_vector_type(2)));

namespace {
constexpr int Bb = 4, Tt = 2048, Cc = 1024, Hh = 16, Dd = 64;
constexpr int ROWS = Bb * Tt;   // 8192
constexpr int C3 = 3 * Cc;      // 3072
constexpr float LNEPS = 1e-5f;
constexpr float SCL2 = 0.18033688011112042f; // 0.125 * log2(e)
}

__device__ __forceinline__ u16 f2bf(float f) {
  union { float f; unsigned u; } v; v.f = f;
  return (u16)((v.u + 0x7fffu + ((v.u >> 16) & 1u)) >> 16);
}
__device__ __forceinline__ u16 bfn(float f) {
  union { __bf16 b; u16 u; } t; t.b = (__bf16)f; return t.u;
}
__device__ __forceinline__ unsigned pk2(float lo, float hi) {
  union { __bf16 b[2]; unsigned u; } t;
  t.b[0] = (__bf16)lo; t.b[1] = (__bf16)hi;
  return t.u;
}
__device__ __forceinline__ float exp2_hw(float x) {
  float r;
  asm("v_exp_f32 %0, %1" : "=v"(r) : "v"(x));
  return r;
}
__device__ __forceinline__ uint2v plswap(unsigned a, unsigned b) {
  return __builtin_amdgcn_permlane32_swap(a, b, false, false);
}
__device__ __forceinline__ float xhalf_max(float x) {
  union { float f; unsigned u; } c; c.f = x;
  uint2v r = plswap(c.u, c.u);
  union { unsigned u; float f; } a, b; a.u = r[0]; b.u = r[1];
  return fmaxf(a.f, b.f);
}
__device__ __forceinline__ float xhalf_sum(float x) {
  union { float f; unsigned u; } c; c.f = x;
  uint2v r = plswap(c.u, c.u);
  union { unsigned u; float f; } a, b; a.u = r[0]; b.u = r[1];
  return a.f + b.f;
}

typedef __attribute__((address_space(3))) unsigned lds_u32;
typedef __attribute__((address_space(1))) const unsigned glb_u32;
__device__ __forceinline__ void gload_lds16(const u16* g, u16* l) {
  __builtin_amdgcn_global_load_lds((glb_u32*)g, (lds_u32*)l, 16, 0, 0);
}

// ---------------- LayerNorm: one wave per row (no LDS, no block barrier) ----------------
__global__ __launch_bounds__(256) void ln_kernel(
    const float* __restrict__ x, const float* __restrict__ g,
    const float* __restrict__ b, u16* __restrict__ out)
{
  const int row = blockIdx.x * 4 + (threadIdx.x >> 6);
  const int l   = threadIdx.x & 63;
  const float4* xr = reinterpret_cast<const float4*>(x + (size_t)row * Cc);
  float4 v[4];
  float s = 0.f, ss = 0.f;
#pragma unroll
  for (int i = 0; i < 4; i++) {
    v[i] = xr[l + i * 64];
    s  += v[i].x + v[i].y + v[i].z + v[i].w;
    ss += v[i].x * v[i].x + v[i].y * v[i].y + v[i].z * v[i].z + v[i].w * v[i].w;
  }
#pragma unroll
  for (int off = 1; off < 64; off <<= 1) {
    s  += __shfl_xor(s, off);
    ss += __shfl_xor(ss, off);
  }
  const float mu   = s * (1.0f / Cc);
  const float var  = ss * (1.0f / Cc) - mu * mu;
  const float rstd = rsqrtf(var + LNEPS);
  const float4* gp = reinterpret_cast<const float4*>(g);
  const float4* bp = reinterpret_cast<const float4*>(b);
  ushort4* op = reinterpret_cast<ushort4*>(out + (size_t)row * Cc);
#pragma unroll
  for (int i = 0; i < 4; i++) {
    const float4 gv = gp[l + i * 64];
    const float4 bv = bp[l + i * 64];
    ushort4 o;
    o.x = f2bf((v[i].x - mu) * rstd * gv.x + bv.x);
    o.y = f2bf((v[i].y - mu) * rstd * gv.y + bv.y);
    o.z = f2bf((v[i].z - mu) * rstd * gv.z + bv.z);
    o.w = f2bf((v[i].w - mu) * rstd * gv.w + bv.w);
    op[l + i * 64] = o;
  }
}

// ---------------- merged weight transpose+cast: 4 matrices, one launch ----------------
__global__ __launch_bounds__(256) void wcast_all(
    const float* __restrict__ w0, u16* __restrict__ o0,   // 1024x3072
    const float* __restrict__ w1, u16* __restrict__ o1,   // 1024x1024
    const float* __restrict__ w2, u16* __restrict__ o2,   // 1024x4096
    const float* __restrict__ w3, u16* __restrict__ o3)   // 4096x1024
{
  int bi = blockIdx.x;
  const float* w; u16* wt; int K, N, nbx;
  if (bi < 3072)      { w = w0; wt = o0; K = 1024; N = 3072; nbx = 96; }
  else if (bi < 4096) { bi -= 3072; w = w1; wt = o1; K = 1024; N = 1024; nbx = 32; }
  else if (bi < 8192) { bi -= 4096; w = w2; wt = o2; K = 1024; N = 4096; nbx = 128; }
  else                { bi -= 8192; w = w3; wt = o3; K = 4096; N = 1024; nbx = 32; }
  const int n0 = (bi % nbx) * 32, k0 = (bi / nbx) * 32;

  __shared__ float tile[32][33];
  const int tx = threadIdx.x & 31, ty = threadIdx.x >> 5; // 32x8
#pragma unroll
  for (int i = 0; i < 4; i++)
    tile[ty + i * 8][tx] = w[(size_t)(k0 + ty + i * 8) * N + n0 + tx];
  __syncthreads();
#pragma unroll
  for (int i = 0; i < 4; i++)
    wt[(size_t)(n0 + ty + i * 8) * K + k0 + tx] = f2bf(tile[tx][ty + i * 8]);
}

enum { EPI_BIAS_BF16 = 0, EPI_BIAS_RELU_BF16 = 1, EPI_BIAS_RES_F32 = 2 };

// ---------------- GEMM 256x256 8-phase counted-vmcnt (QKV / FC1) ----------------
template <int EPI, bool FVT>
__global__ __launch_bounds__(512, 1) void gemm8p(
    const u16* __restrict__ A, const u16* __restrict__ Bt,
    const float* __restrict__ bias, const float* __restrict__ res,
    void* __restrict__ outp, u16* __restrict__ vtout, int M, int N, int K)
{
  __shared__ alignas(16) u16 Asl[2][2][128 * 64];
  __shared__ alignas(16) u16 Bsl[2][2][128 * 64];

  const int tid = threadIdx.x;
  const int l   = tid & 63;
  const int wv  = tid >> 6;
  const int wr  = wv >> 2;
  const int wc  = wv & 3;
  const int lr  = l & 15;
  const int lg  = (l >> 4) & 3;

  const int xcd = (int)blockIdx.x & 7;
  const int j   = (int)blockIdx.x >> 3;
  const int nbn = N >> 8;
  const int bmpx = ((int)gridDim.x >> 3) / nbn;
  const int bm = (xcd * bmpx + j / nbn) << 8;
  const int bn = (j % nbn) << 8;

  const int srw = wv * 8 + (l >> 3);
  const int sch = ((l & 7) ^ ((l >> 3) & 7)) * 8;
  const int dst = (l & 7) * 8;

  const int csw0 = (lg ^ (lr & 7)) * 8;
  const int csw1 = ((4 + lg) ^ (lr & 7)) * 8;
  const int ar = wr * 64;
  const int br = wc * 32;

  f32x4 acc[8][4];
#pragma unroll
  for (int mi = 0; mi < 8; mi++)
#pragma unroll
    for (int nj = 0; nj < 4; nj++)
      acc[mi][nj] = (f32x4){0.f, 0.f, 0.f, 0.f};

  const int NT = K >> 6;

  auto stA = [&](int h, int tt) {
#pragma unroll
    for (int L = 0; L < 2; ++L)
      gload_lds16(A + (size_t)(bm + h * 128 + L * 64 + srw) * K + tt * 64 + sch,
                  &Asl[tt & 1][h][(L * 64 + srw) * 64 + dst]);
  };
  auto stB = [&](int h, int tt) {
#pragma unroll
    for (int L = 0; L < 2; ++L)
      gload_lds16(Bt + (size_t)(bn + h * 128 + L * 64 + srw) * K + tt * 64 + sch,
                  &Bsl[tt & 1][h][(L * 64 + srw) * 64 + dst]);
  };

  stA(0, 0); stB(0, 0); stB(1, 0); stA(1, 0);
  asm volatile("s_waitcnt vmcnt(4)" ::: "memory");
  asm volatile("s_barrier" ::: "memory");

  bf16x8 af[4][2], bfr[2][2][2];

  for (int t = 0; t < NT; ++t) {
    const int cb = t & 1;
    const bool st = (t + 1 < NT);
    const u16* Ah0 = &Asl[cb][0][0];
    const u16* Ah1 = &Asl[cb][1][0];
    const u16* Bh0 = &Bsl[cb][0][0];
    const u16* Bh1 = &Bsl[cb][1][0];

    // ---- P1 ----
#pragma unroll
    for (int m = 0; m < 4; ++m) {
      af[m][0] = *reinterpret_cast<const bf16x8*>(Ah0 + (ar + m * 16 + lr) * 64 + csw0);
      af[m][1] = *reinterpret_cast<const bf16x8*>(Ah0 + (ar + m * 16 + lr) * 64 + csw1);
    }
#pragma unroll
    for (int n = 0; n < 2; ++n) {
      bfr[0][n][0] = *reinterpret_cast<const bf16x8*>(Bh0 + (br + n * 16 + lr) * 64 + csw0);
      bfr[0][n][1] = *reinterpret_cast<const bf16x8*>(Bh0 + (br + n * 16 + lr) * 64 + csw1);
    }
    if (st) { stA(0, t + 1); stB(0, t + 1); }
    asm volatile("s_barrier" ::: "memory");
    __builtin_amdgcn_s_setprio(1);
#pragma unroll
    for (int m = 0; m < 4; ++m)
#pragma unroll
      for (int n = 0; n < 2; ++n) {
        acc[m][n] = __builtin_amdgcn_mfma_f32_16x16x32_bf16(af[m][0], bfr[0][n][0], acc[m][n], 0, 0, 0);
        acc[m][n] = __builtin_amdgcn_mfma_f32_16x16x32_bf16(af[m][1], bfr[0][n][1], acc[m][n], 0, 0, 0);
      }
    __builtin_amdgcn_s_setprio(0);
    if (st) asm volatile("s_waitcnt vmcnt(6)" ::: "memory");
    else    asm volatile("s_waitcnt vmcnt(2)" ::: "memory");
    asm volatile("s_barrier" ::: "memory");

    // ---- P2 ----
#pragma unroll
    for (int n = 0; n < 2; ++n) {
      bfr[1][n][0] = *reinterpret_cast<const bf16x8*>(Bh1 + (br + n * 16 + lr) * 64 + csw0);
      bfr[1][n][1] = *reinterpret_cast<const bf16x8*>(Bh1 + (br + n * 16 + lr) * 64 + csw1);
    }
    if (st) stB(1, t + 1);
    asm volatile("s_barrier" ::: "memory");
    __builtin_amdgcn_s_setprio(1);
#pragma unroll
    for (int m = 0; m < 4; ++m)
#pragma unroll
      for (int n = 0; n < 2; ++n) {
        acc[m][2 + n] = __builtin_amdgcn_mfma_f32_16x16x32_bf16(af[m][0], bfr[1][n][0], acc[m][2 + n], 0, 0, 0);
        acc[m][2 + n] = __builtin_amdgcn_mfma_f32_16x16x32_bf16(af[m][1], bfr[1][n][1], acc[m][2 + n], 0, 0, 0);
      }
    __builtin_amdgcn_s_setprio(0);
    if (st) asm volatile("s_waitcnt vmcnt(6)" ::: "memory");
    else    asm volatile("s_waitcnt vmcnt(0)" ::: "memory");
    asm volatile("s_barrier" ::: "memory");

    // ---- P3 ----
#pragma unroll
    for (int m = 0; m < 4; ++m) {
      af[m][0] = *reinterpret_cast<const bf16x8*>(Ah1 + (ar + m * 16 + lr) * 64 + csw0);
      af[m][1] = *reinterpret_cast<const bf16x8*>(Ah1 + (ar + m * 16 + lr) * 64 + csw1);
    }
    if (st) stA(1, t + 1);
    asm volatile("s_barrier" ::: "memory");
    __builtin_amdgcn_s_setprio(1);
#pragma unroll
    for (int m = 0; m < 4; ++m)
#pragma unroll
      for (int n = 0; n < 2; ++n) {
        acc[4 + m][n] = __builtin_amdgcn_mfma_f32_16x16x32_bf16(af[m][0], bfr[0][n][0], acc[4 + m][n], 0, 0, 0);
        acc[4 + m][n] = __builtin_amdgcn_mfma_f32_16x16x32_bf16(af[m][1], bfr[0][n][1], acc[4 + m][n], 0, 0, 0);
      }
    __builtin_amdgcn_s_setprio(0);
    asm volatile("s_barrier" ::: "memory");

    // ---- P4 ----
    __builtin_amdgcn_s_setprio(1);
#pragma unroll
    for (int m = 0; m < 4; ++m)
#pragma unroll
      for (int n = 0; n < 2; ++n) {
        acc[4 + m][2 + n] = __builtin_amdgcn_mfma_f32_16x16x32_bf16(af[m][0], bfr[1][n][0], acc[4 + m][2 + n], 0, 0, 0);
        acc[4 + m][2 + n] = __builtin_amdgcn_mfma_f32_16x16x32_bf16(af[m][1], bfr[1][n][1], acc[4 + m][2 + n], 0, 0, 0);
      }
    __builtin_amdgcn_s_setprio(0);
    if (st) asm volatile("s_waitcnt vmcnt(4)" ::: "memory");
    asm volatile("s_barrier" ::: "memory");
  }

  // epilogue
#pragma unroll
  for (int mi = 0; mi < 8; ++mi) {
    const int row0 = bm + (mi >> 2) * 128 + wr * 64 + (mi & 3) * 16 + lg * 4;
#pragma unroll
    for (int nj = 0; nj < 4; ++nj) {
      const int col = bn + (nj >> 1) * 128 + wc * 32 + (nj & 1) * 16 + lr;
      const float bv = bias[col];
      u16 ov[4];
#pragma unroll
      for (int r = 0; r < 4; ++r) {
        const int row = row0 + r;
        float v = acc[mi][nj][r] + bv;
        if constexpr (EPI == EPI_BIAS_RELU_BF16) v = fmaxf(v, 0.0f);
        if constexpr (EPI == EPI_BIAS_RES_F32) {
          float* out = (float*)outp;
          out[(size_t)row * N + col] = v + res[(size_t)row * N + col];
        } else {
          ov[r] = f2bf(v);
          ((u16*)outp)[(size_t)row * N + col] = ov[r];
        }
      }
      if constexpr (FVT) {
        if (col >= 2 * Cc) {   // V columns -> vt[b][h][d][t], t = row&2047
          const int bq = row0 >> 11;
          const int t0 = row0 & 2047;
          const int hh2 = (col - 2 * Cc) >> 6;
          const int dd2 = col & 63;
          union { u16 u[4]; ushort4 v4; } pkv;
          pkv.u[0] = ov[0]; pkv.u[1] = ov[1]; pkv.u[2] = ov[2]; pkv.u[3] = ov[3];
          *reinterpret_cast<ushort4*>(
              &vtout[((size_t)(bq * Hh + hh2) * Dd + dd2) * Tt + t0]) = pkv.v4;
        }
      }
    }
  }
}

// ---------------- GEMM 128x128 (proj / FC2): m97 + T2 swizzle + L2 remap ----------------
template <int EPI>
__global__ __launch_bounds__(256, 3) void gemm_bt2(
    const u16* __restrict__ A, const u16* __restrict__ Bt,
    const float* __restrict__ bias, const float* __restrict__ res,
    void* __restrict__ outp, int M, int N, int K)
{
  constexpr int BM = 128, BN = 128, BK = 64;
  __shared__ alignas(16) u16 As[BM][BK];
  __shared__ alignas(16) u16 Bs[BN][BK];
  const int tid  = threadIdx.x;
  const int lane = tid & 63;
  const int wv   = tid >> 6;
  const int wr   = wv >> 1, wc = wv & 1;
  const int lr   = lane & 15, lg = lane >> 4;

  const int xcd = (int)blockIdx.x & 7;
  const int j   = (int)blockIdx.x >> 3;
  const int nbn = N >> 7;
  const int bmpx = ((int)gridDim.x >> 3) / nbn;
  const int bm = (xcd * bmpx + j / nbn) << 7;
  const int bn = (j % nbn) << 7;

  f32x4 acc[4][4];
#pragma unroll
  for (int mi = 0; mi < 4; mi++)
#pragma unroll
    for (int nj = 0; nj < 4; nj++)
      acc[mi][nj] = (f32x4){0.f, 0.f, 0.f, 0.f};

  const int srow = tid >> 3;
  const int scol = ((tid & 7) ^ (srow & 7)) * 8;
  const u16* ga = &A [(size_t)(bm + srow) * K + scol];
  const u16* gb = &Bt[(size_t)(bn + srow) * K + scol];
  u16* as_dst = &As[0][0] + (size_t)tid * 8;
  u16* bs_dst = &Bs[0][0] + (size_t)tid * 8;

  for (int k0 = 0; k0 < K; k0 += BK) {
#pragma unroll
    for (int p = 0; p < 4; p++) {
      gload_lds16(ga + (size_t)p * 32 * K + k0, as_dst + p * 2048);
      gload_lds16(gb + (size_t)p * 32 * K + k0, bs_dst + p * 2048);
    }
    __syncthreads();
#pragma unroll
    for (int kk = 0; kk < BK; kk += 32) {
      const int cb = kk >> 3;
      const int csw = ((cb + lg) ^ (lr & 7)) * 8;
      bf16x8 af[4], bfr[4];
#pragma unroll
      for (int mi = 0; mi < 4; mi++)
        af[mi] = *reinterpret_cast<const bf16x8*>(&As[wr * 64 + mi * 16 + lr][0] + csw);
#pragma unroll
      for (int nj = 0; nj < 4; nj++)
        bfr[nj] = *reinterpret_cast<const bf16x8*>(&Bs[wc * 64 + nj * 16 + lr][0] + csw);
#pragma unroll
      for (int mi = 0; mi < 4; mi++)
#pragma unroll
        for (int nj = 0; nj < 4; nj++)
          acc[mi][nj] = __builtin_amdgcn_mfma_f32_16x16x32_bf16(af[mi], bfr[nj], acc[mi][nj], 0, 0, 0);
    }
    __syncthreads();
  }

#pragma unroll
  for (int mi = 0; mi < 4; mi++) {
#pragma unroll
    for (int nj = 0; nj < 4; nj++) {
      const int col = bn + wc * 64 + nj * 16 + lr;
      const float bv = bias[col];
#pragma unroll
      for (int r = 0; r < 4; r++) {
        const int row = bm + wr * 64 + mi * 16 + lg * 4 + r;
        float v = acc[mi][nj][r] + bv;
        if constexpr (EPI == EPI_BIAS_RELU_BF16) v = fmaxf(v, 0.0f);
        if constexpr (EPI == EPI_BIAS_RES_F32) {
          float* out = (float*)outp;
          out[(size_t)row * N + col] = v + res[(size_t)row * N + col];
        } else {
          ((u16*)outp)[(size_t)row * N + col] = f2bf(v);
        }
      }
    }
  }
}

// ---------------- flash attention: 64 q-rows/wave, dual-chain, SIMD-paired ----------------
__global__ __launch_bounds__(512, 1) void flash_attn(
    const u16* __restrict__ qkv,   // [B][T][3C]
    const u16* __restrict__ vt,    // [B][H][D][T]
    u16* __restrict__ y)           // [B][T][C]
{
  const int tid = threadIdx.x, lane = tid & 63, wv = tid >> 6;
  const int l31 = lane & 31, hf = lane >> 5;

  const int bid = blockIdx.x;
  const int lid = (bid & 7) * 32 + (bid >> 3);
  const int bh = lid >> 2, pg = lid & 3;
  const int b = bh >> 4, h = bh & 15;
  const int sbase = pg * 4 + (wv & 3);
  const int s = (wv < 4) ? sbase : (31 - sbase);

  const u16* qbase = qkv + (size_t)b * Tt * C3 + h * Dd;
  const u16* kbase = qbase + Cc;
  const u16* vbase = vt + (size_t)bh * Dd * Tt;

  bool dmask[16];
#pragma unroll
  for (int r = 0; r < 16; r++)
    dmask[r] = ((r & 3) + 8 * (r >> 2) + 4 * hf) > l31;

  const int qa0 = s * 64;
  const int qb0 = qa0 + 32;
  const int ta = 2 * s;

  bf16x8 qfa[4], qfb[4];
#pragma unroll
  for (int kc = 0; kc < 4; kc++) {
    qfa[kc] = *reinterpret_cast<const bf16x8*>(
        &qbase[(size_t)(qa0 + l31) * C3 + kc * 16 + hf * 8]);
    qfb[kc] = *reinterpret_cast<const bf16x8*>(
        &qbase[(size_t)(qb0 + l31) * C3 + kc * 16 + hf * 8]);
  }

  f32x16 oa[2], ob[2];
#pragma unroll
  for (int i = 0; i < 16; i++) { oa[0][i] = 0.f; oa[1][i] = 0.f; ob[0][i] = 0.f; ob[1][i] = 0.f; }
  float mA = -INFINITY, lA = 0.0f, mB = -INFINITY, lB = 0.0f;

  const u16* kptr = &kbase[(size_t)l31 * C3 + hf * 8];
  const u16* vp0 = &vbase[(size_t)l31 * Tt + hf * 8];
  const u16* vp1 = vp0 + (size_t)32 * Tt;

  bf16x8 kf[4];
#pragma unroll
  for (int kc = 0; kc < 4; kc++)
    kf[kc] = *reinterpret_cast<const bf16x8*>(kptr + kc * 16);

  for (int kt = 0; kt <= ta; ++kt) {
    bf16x8 vf[2][2];
#pragma unroll
    for (int ch = 0; ch < 2; ch++) {
      vf[0][ch] = *reinterpret_cast<const bf16x8*>(vp0 + ch * 16);
      vf[1][ch] = *reinterpret_cast<const bf16x8*>(vp1 + ch * 16);
    }
    vp0 += 32; vp1 += 32;

    f32x16 sA, sB;
#pragma unroll
    for (int i = 0; i < 16; i++) { sA[i] = 0.f; sB[i] = 0.f; }
#pragma unroll
    for (int kc = 0; kc < 4; kc++) {
      sA = __builtin_amdgcn_mfma_f32_32x32x16_bf16(kf[kc], qfa[kc], sA, 0, 0, 0);
      sB = __builtin_amdgcn_mfma_f32_32x32x16_bf16(kf[kc], qfb[kc], sB, 0, 0, 0);
    }

    kptr += (size_t)32 * C3;
    bf16x8 kn[4];
#pragma unroll
    for (int kc = 0; kc < 4; kc++)
      kn[kc] = *reinterpret_cast<const bf16x8*>(kptr + kc * 16);

    const bool diagA = (kt == ta);

    float svA[16], svB[16];
#pragma unroll
    for (int r = 0; r < 16; r++) {
      svA[r] = sA[r];
      if (diagA && dmask[r]) svA[r] = -INFINITY;
      svB[r] = sB[r];
    }

    float mAa = fmaxf(fmaxf(svA[0], svA[1]), fmaxf(svA[2], svA[3]));
    float mAb = fmaxf(fmaxf(svA[4], svA[5]), fmaxf(svA[6], svA[7]));
    float mAc = fmaxf(fmaxf(svA[8], svA[9]), fmaxf(svA[10], svA[11]));
    float mAd = fmaxf(fmaxf(svA[12], svA[13]), fmaxf(svA[14], svA[15]));
    float m8A = fmaxf(fmaxf(mAa, mAb), fmaxf(mAc, mAd));
    float mBa = fmaxf(fmaxf(svB[0], svB[1]), fmaxf(svB[2], svB[3]));
    float mBb = fmaxf(fmaxf(svB[4], svB[5]), fmaxf(svB[6], svB[7]));
    float mBc = fmaxf(fmaxf(svB[8], svB[9]), fmaxf(svB[10], svB[11]));
    float mBd = fmaxf(fmaxf(svB[12], svB[13]), fmaxf(svB[14], svB[15]));
    float m8B = fmaxf(fmaxf(mBa, mBb), fmaxf(mBc, mBd));
    m8A = xhalf_max(m8A);
    m8B = xhalf_max(m8B);

    if (!__all(m8A - mA <= 64.0f)) {
      const float mnew  = fmaxf(mA, m8A);
      const float alpha = exp2_hw((mA - mnew) * SCL2);
      lA *= alpha;
#pragma unroll
      for (int i = 0; i < 16; i++) { oa[0][i] *= alpha; oa[1][i] *= alpha; }
      mA = mnew;
    }
    if (!__all(m8B - mB <= 64.0f)) {
      const float mnew  = fmaxf(mB, m8B);
      const float alpha = exp2_hw((mB - mnew) * SCL2);
      lB *= alpha;
#pragma unroll
      for (int i = 0; i < 16; i++) { ob[0][i] *= alpha; ob[1][i] *= alpha; }
      mB = mnew;
    }

    const float msA = mA * SCL2;
    const float msB = mB * SCL2;
    float pA[16], pB[16];
#pragma unroll
    for (int r = 0; r < 16; r++) {
      pA[r] = exp2_hw(fmaf(svA[r], SCL2, -msA));
      pB[r] = exp2_hw(fmaf(svB[r], SCL2, -msB));
    }
    {
      float a0 = ((pA[0] + pA[1]) + (pA[2] + pA[3])) + ((pA[4] + pA[5]) + (pA[6] + pA[7]));
      float a1 = ((pA[8] + pA[9]) + (pA[10] + pA[11])) + ((pA[12] + pA[13]) + (pA[14] + pA[15]));
      lA += a0 + a1;
      float b0 = ((pB[0] + pB[1]) + (pB[2] + pB[3])) + ((pB[4] + pB[5]) + (pB[6] + pB[7]));
      float b1 = ((pB[8] + pB[9]) + (pB[10] + pB[11])) + ((pB[12] + pB[13]) + (pB[14] + pB[15]));
      lB += b0 + b1;
    }

    unsigned pwA[2][4], pwB[2][4];
#pragma unroll
    for (int ch = 0; ch < 2; ch++) {
      const int bs = ch * 8;
      {
        unsigned w0 = pk2(pA[bs + 0], pA[bs + 1]);
        unsigned w1 = pk2(pA[bs + 2], pA[bs + 3]);
        unsigned w2 = pk2(pA[bs + 4], pA[bs + 5]);
        unsigned w3 = pk2(pA[bs + 6], pA[bs + 7]);
        uint2v r02 = plswap(w0, w2);
        uint2v r13 = plswap(w1, w3);
        pwA[ch][0] = r02[0]; pwA[ch][2] = r02[1];
        pwA[ch][1] = r13[0]; pwA[ch][3] = r13[1];
      }
      {
        unsigned w0 = pk2(pB[bs + 0], pB[bs + 1]);
        unsigned w1 = pk2(pB[bs + 2], pB[bs + 3]);
        unsigned w2 = pk2(pB[bs + 4], pB[bs + 5]);
        unsigned w3 = pk2(pB[bs + 6], pB[bs + 7]);
        uint2v r02 = plswap(w0, w2);
        uint2v r13 = plswap(w1, w3);
        pwB[ch][0] = r02[0]; pwB[ch][2] = r02[1];
        pwB[ch][1] = r13[0]; pwB[ch][3] = r13[1];
      }
    }

#pragma unroll
    for (int d0i = 0; d0i < 2; d0i++)
#pragma unroll
      for (int ch = 0; ch < 2; ch++) {
        union { unsigned w[4]; bf16x8 v; } pa, pb;
        pa.w[0] = pwA[ch][0]; pa.w[1] = pwA[ch][1];
        pa.w[2] = pwA[ch][2]; pa.w[3] = pwA[ch][3];
        pb.w[0] = pwB[ch][0]; pb.w[1] = pwB[ch][1];
        pb.w[2] = pwB[ch][2]; pb.w[3] = pwB[ch][3];
        oa[d0i] = __builtin_amdgcn_mfma_f32_32x32x16_bf16(vf[d0i][ch], pa.v, oa[d0i], 0, 0, 0);
        ob[d0i] = __builtin_amdgcn_mfma_f32_32x32x16_bf16(vf[d0i][ch], pb.v, ob[d0i], 0, 0, 0);
      }

#pragma unroll
    for (int kc = 0; kc < 4; kc++) kf[kc] = kn[kc];
  }

  // peeled tile: group B only, diagonal-masked
  {
    bf16x8 vf[2][2];
#pragma unroll
    for (int ch = 0; ch < 2; ch++) {
      vf[0][ch] = *reinterpret_cast<const bf16x8*>(vp0 + ch * 16);
      vf[1][ch] = *reinterpret_cast<const bf16x8*>(vp1 + ch * 16);
    }

    f32x16 sB;
#pragma unroll
    for (int i = 0; i < 16; i++) sB[i] = 0.f;
#pragma unroll
    for (int kc = 0; kc < 4; kc++)
      sB = __builtin_amdgcn_mfma_f32_32x32x16_bf16(kf[kc], qfb[kc], sB, 0, 0, 0);

    float svB[16];
#pragma unroll
    for (int r = 0; r < 16; r++) {
      svB[r] = sB[r];
      if (dmask[r]) svB[r] = -INFINITY;
    }
    float mBa = fmaxf(fmaxf(svB[0], svB[1]), fmaxf(svB[2], svB[3]));
    float mBb = fmaxf(fmaxf(svB[4], svB[5]), fmaxf(svB[6], svB[7]));
    float mBc = fmaxf(fmaxf(svB[8], svB[9]), fmaxf(svB[10], svB[11]));
    float mBd = fmaxf(fmaxf(svB[12], svB[13]), fmaxf(svB[14], svB[15]));
    float m8B = fmaxf(fmaxf(mBa, mBb), fmaxf(mBc, mBd));
    m8B = xhalf_max(m8B);

    if (!__all(m8B - mB <= 64.0f)) {
      const float mnew  = fmaxf(mB, m8B);
      const float alpha = exp2_hw((mB - mnew) * SCL2);
      lB *= alpha;
#pragma unroll
      for (int i = 0; i < 16; i++) { ob[0][i] *= alpha; ob[1][i] *= alpha; }
      mB = mnew;
    }
    const float msB = mB * SCL2;
    float pB[16];
#pragma unroll
    for (int r = 0; r < 16; r++)
      pB[r] = exp2_hw(fmaf(svB[r], SCL2, -msB));
    {
      float b0 = ((pB[0] + pB[1]) + (pB[2] + pB[3])) + ((pB[4] + pB[5]) + (pB[6] + pB[7]));
      float b1 = ((pB[8] + pB[9]) + (pB[10] + pB[11])) + ((pB[12] + pB[13]) + (pB[14] + pB[15]));
      lB += b0 + b1;
    }
    unsigned pwB[2][4];
#pragma unroll
    for (int ch = 0; ch < 2; ch++) {
      const int bs = ch * 8;
      unsigned w0 = pk2(pB[bs + 0], pB[bs + 1]);
      unsigned w1 = pk2(pB[bs + 2], pB[bs + 3]);
      unsigned w2 = pk2(pB[bs + 4], pB[bs + 5]);
      unsigned w3 = pk2(pB[bs + 6], pB[bs + 7]);
      uint2v r02 = plswap(w0, w2);
      uint2v r13 = plswap(w1, w3);
      pwB[ch][0] = r02[0]; pwB[ch][2] = r02[1];
      pwB[ch][1] = r13[0]; pwB[ch][3] = r13[1];
    }
#pragma unroll
    for (int d0i = 0; d0i < 2; d0i++)
#pragma unroll
      for (int ch = 0; ch < 2; ch++) {
        union { unsigned w[4]; bf16x8 v; } pb;
        pb.w[0] = pwB[ch][0]; pb.w[1] = pwB[ch][1];
        pb.w[2] = pwB[ch][2]; pb.w[3] = pwB[ch][3];
        ob[d0i] = __builtin_amdgcn_mfma_f32_32x32x16_bf16(vf[d0i][ch], pb.v, ob[d0i], 0, 0, 0);
      }
  }

  {
    const float lsA = xhalf_sum(lA);
    const float invA = 1.0f / lsA;
    u16* yrow = y + (size_t)(b * Tt + qa0 + l31) * Cc + h * Dd;
#pragma unroll
    for (int d0i = 0; d0i < 2; d0i++)
#pragma unroll
      for (int qd = 0; qd < 4; qd++) {
        ushort4 o;
        o.x = bfn(oa[d0i][qd * 4 + 0] * invA);
        o.y = bfn(oa[d0i][qd * 4 + 1] * invA);
        o.z = bfn(oa[d0i][qd * 4 + 2] * invA);
        o.w = bfn(oa[d0i][qd * 4 + 3] * invA);
        *reinterpret_cast<ushort4*>(&yrow[d0i * 32 + qd * 8 + hf * 4]) = o;
      }
  }
  {
    const float lsB = xhalf_sum(lB);
    const float invB = 1.0f / lsB;
    u16* yrow = y + (size_t)(b * Tt + qb0 + l31) * Cc + h * Dd;
#pragma unroll
    for (int d0i = 0; d0i < 2; d0i++)
#pragma unroll
      for (int qd = 0; qd < 4; qd++) {
        ushort4 o;
        o.x = bfn(ob[d0i][qd * 4 + 0] * invB);
        o.y = bfn(ob[d0i][qd * 4 + 1] * invB);
        o.z = bfn(ob[d0i][qd * 4 + 2] * invB);
        o.w = bfn(ob[d0i][qd * 4 + 3] * invB);
        *reinterpret_cast<ushort4*>(&yrow[d0i * 32 + qd * 8 + hf * 4]) = o;
      }
  }
}

// ---------------- launch ----------------
extern "C" void kernel_launch(void* const* d_in, const int* in_sizes, int n_in,
                              void* d_out, int out_size, void* d_ws, size_t ws_size,
                              hipStream_t stream)
{
  const float* x      = (const float*)d_in[0];
  const float* ln1_g  = (const float*)d_in[1];
  const float* ln1_b  = (const float*)d_in[2];
  const float* attn_w = (const float*)d_in[3];
  const float* attn_b = (const float*)d_in[4];
  const float* proj_w = (const float*)d_in[5];
  const float* proj_b = (const float*)d_in[6];
  const float* ln2_g  = (const float*)d_in[7];
  const float* ln2_b  = (const float*)d_in[8];
  const float* fc1_w  = (const float*)d_in[9];
  const float* fc1_b  = (const float*)d_in[10];
  const float* fc2_w  = (const float*)d_in[11];
  const float* fc2_b  = (const float*)d_in[12];
  float* out = (float*)d_out;

  char* ws = (char*)d_ws;
  size_t o = 0;
  auto alloc = [&](size_t bytes) { char* p = ws + o; o += bytes; return p; };
  u16* wqkv_t  = (u16*)alloc((size_t)C3 * Cc * 2);
  u16* wproj_t = (u16*)alloc((size_t)Cc * Cc * 2);
  u16* wfc1_t  = (u16*)alloc((size_t)4096 * Cc * 2);
  u16* wfc2_t  = (u16*)alloc((size_t)Cc * 4096 * 2);
  u16* h_bf    = (u16*)alloc((size_t)ROWS * Cc * 2);
  u16* y_bf    = (u16*)alloc((size_t)ROWS * Cc * 2);
  u16* qkv_raw = (u16*)alloc((size_t)ROWS * C3 * 2);
  u16* vt      = (u16*)alloc((size_t)Bb * Hh * Dd * Tt * 2);
  u16* hh      = qkv_raw; // aliases qkv_raw+vt, both dead by FC1 time

  wcast_all<<<12288, 256, 0, stream>>>(attn_w, wqkv_t, proj_w, wproj_t,
                                       fc1_w, wfc1_t, fc2_w, wfc2_t);

  ln_kernel<<<ROWS / 4, 256, 0, stream>>>(x, ln1_g, ln1_b, h_bf);
  gemm8p<EPI_BIAS_BF16, true><<<8 * (ROWS / 256 / 8) * (C3 / 256), 512, 0, stream>>>(
      h_bf, wqkv_t, attn_b, nullptr, qkv_raw, vt, ROWS, C3, Cc);
  flash_attn<<<dim3(256), 512, 0, stream>>>(qkv_raw, vt, y_bf);
  gemm_bt2<EPI_BIAS_RES_F32><<<64 * (Cc / 128), 256, 0, stream>>>(
      y_bf, wproj_t, proj_b, x, out, ROWS, Cc, Cc);
  ln_kernel<<<ROWS / 4, 256, 0, stream>>>(out, ln2_g, ln2_b, h_bf);
  gemm8p<EPI_BIAS_RELU_BF16, false><<<8 * (ROWS / 256 / 8) * (4096 / 256), 512, 0, stream>>>(
      h_bf, wfc1_t, fc1_b, nullptr, hh, nullptr, ROWS, 4096, Cc);
  gemm_bt2<EPI_BIAS_RES_F32><<<64 * (Cc / 128), 256, 0, stream>>>(
      hh, wfc2_t, fc2_b, out, out, ROWS, Cc, 4096);
}

// Round 22
// 346.897 us; speedup vs baseline: 1.0023x; 1.0010x over previous
//
#include <hip/hip_runtime.h>
#include <cstdint>
#include <cstddef>

typedef __bf16 bf16x8 __attribute__((ext_vector_type(8)));
typedef float f32x4 __attribute__((ext_vector_type(4)));
typedef float f32x16 __attribute__((ext_vector_type(16)));
typedef unsigned short u16;
typedef unsigned uint2v __attribute__((ext_vector_type(2)));

namespace {
constexpr int Bb = 4, Tt = 2048, Cc = 1024, Hh = 16, Dd = 64;
constexpr int ROWS = Bb * Tt;   // 8192
constexpr int C3 = 3 * Cc;      // 3072
constexpr float LNEPS = 1e-5f;
constexpr float SCL2 = 0.18033688011112042f; // 0.125 * log2(e)
}

__device__ __forceinline__ u16 f2bf(float f) {
  union { float f; unsigned u; } v; v.f = f;
  return (u16)((v.u + 0x7fffu + ((v.u >> 16) & 1u)) >> 16);
}
__device__ __forceinline__ u16 bfn(float f) {
  union { __bf16 b; u16 u; } t; t.b = (__bf16)f; return t.u;
}
__device__ __forceinline__ unsigned pk2(float lo, float hi) {
  union { __bf16 b[2]; unsigned u; } t;
  t.b[0] = (__bf16)lo; t.b[1] = (__bf16)hi;
  return t.u;
}
__device__ __forceinline__ float exp2_hw(float x) {
  float r;
  asm("v_exp_f32 %0, %1" : "=v"(r) : "v"(x));
  return r;
}
__device__ __forceinline__ uint2v plswap(unsigned a, unsigned b) {
  return __builtin_amdgcn_permlane32_swap(a, b, false, false);
}
__device__ __forceinline__ float xhalf_max(float x) {
  union { float f; unsigned u; } c; c.f = x;
  uint2v r = plswap(c.u, c.u);
  union { unsigned u; float f; } a, b; a.u = r[0]; b.u = r[1];
  return fmaxf(a.f, b.f);
}
__device__ __forceinline__ float xhalf_sum(float x) {
  union { float f; unsigned u; } c; c.f = x;
  uint2v r = plswap(c.u, c.u);
  union { unsigned u; float f; } a, b; a.u = r[0]; b.u = r[1];
  return a.f + b.f;
}

typedef __attribute__((address_space(3))) unsigned lds_u32;
typedef __attribute__((address_space(1))) const unsigned glb_u32;
__device__ __forceinline__ void gload_lds16(const u16* g, u16* l) {
  __builtin_amdgcn_global_load_lds((glb_u32*)g, (lds_u32*)l, 16, 0, 0);
}

// ---------------- LayerNorm: one wave per row (no LDS, no block barrier) ----------------
__global__ __launch_bounds__(256) void ln_kernel(
    const float* __restrict__ x, const float* __restrict__ g,
    const float* __restrict__ b, u16* __restrict__ out)
{
  const int row = blockIdx.x * 4 + (threadIdx.x >> 6);
  const int l   = threadIdx.x & 63;
  const float4* xr = reinterpret_cast<const float4*>(x + (size_t)row * Cc);
  float4 v[4];
  float s = 0.f, ss = 0.f;
#pragma unroll
  for (int i = 0; i < 4; i++) {
    v[i] = xr[l + i * 64];
    s  += v[i].x + v[i].y + v[i].z + v[i].w;
    ss += v[i].x * v[i].x + v[i].y * v[i].y + v[i].z * v[i].z + v[i].w * v[i].w;
  }
#pragma unroll
  for (int off = 1; off < 64; off <<= 1) {
    s  += __shfl_xor(s, off);
    ss += __shfl_xor(ss, off);
  }
  const float mu   = s * (1.0f / Cc);
  const float var  = ss * (1.0f / Cc) - mu * mu;
  const float rstd = rsqrtf(var + LNEPS);
  const float4* gp = reinterpret_cast<const float4*>(g);
  const float4* bp = reinterpret_cast<const float4*>(b);
  ushort4* op = reinterpret_cast<ushort4*>(out + (size_t)row * Cc);
#pragma unroll
  for (int i = 0; i < 4; i++) {
    const float4 gv = gp[l + i * 64];
    const float4 bv = bp[l + i * 64];
    ushort4 o;
    o.x = f2bf((v[i].x - mu) * rstd * gv.x + bv.x);
    o.y = f2bf((v[i].y - mu) * rstd * gv.y + bv.y);
    o.z = f2bf((v[i].z - mu) * rstd * gv.z + bv.z);
    o.w = f2bf((v[i].w - mu) * rstd * gv.w + bv.w);
    op[l + i * 64] = o;
  }
}

// ---------------- merged weight transpose+cast: 4 matrices, one launch ----------------
__global__ __launch_bounds__(256) void wcast_all(
    const float* __restrict__ w0, u16* __restrict__ o0,   // 1024x3072
    const float* __restrict__ w1, u16* __restrict__ o1,   // 1024x1024
    const float* __restrict__ w2, u16* __restrict__ o2,   // 1024x4096
    const float* __restrict__ w3, u16* __restrict__ o3)   // 4096x1024
{
  int bi = blockIdx.x;
  const float* w; u16* wt; int K, N, nbx;
  if (bi < 3072)      { w = w0; wt = o0; K = 1024; N = 3072; nbx = 96; }
  else if (bi < 4096) { bi -= 3072; w = w1; wt = o1; K = 1024; N = 1024; nbx = 32; }
  else if (bi < 8192) { bi -= 4096; w = w2; wt = o2; K = 1024; N = 4096; nbx = 128; }
  else                { bi -= 8192; w = w3; wt = o3; K = 4096; N = 1024; nbx = 32; }
  const int n0 = (bi % nbx) * 32, k0 = (bi / nbx) * 32;

  __shared__ float tile[32][33];
  const int tx = threadIdx.x & 31, ty = threadIdx.x >> 5; // 32x8
#pragma unroll
  for (int i = 0; i < 4; i++)
    tile[ty + i * 8][tx] = w[(size_t)(k0 + ty + i * 8) * N + n0 + tx];
  __syncthreads();
#pragma unroll
  for (int i = 0; i < 4; i++)
    wt[(size_t)(n0 + ty + i * 8) * K + k0 + tx] = f2bf(tile[tx][ty + i * 8]);
}

enum { EPI_BIAS_BF16 = 0, EPI_BIAS_RELU_BF16 = 1, EPI_BIAS_RES_F32 = 2 };

// ---------------- GEMM 256x256 8-phase counted-vmcnt (QKV / FC1) ----------------
template <int EPI, bool FVT>
__global__ __launch_bounds__(512, 1) void gemm8p(
    const u16* __restrict__ A, const u16* __restrict__ Bt,
    const float* __restrict__ bias, const float* __restrict__ res,
    void* __restrict__ outp, u16* __restrict__ vtout, int M, int N, int K)
{
  __shared__ alignas(16) u16 Asl[2][2][128 * 64];
  __shared__ alignas(16) u16 Bsl[2][2][128 * 64];

  const int tid = threadIdx.x;
  const int l   = tid & 63;
  const int wv  = tid >> 6;
  const int wr  = wv >> 2;
  const int wc  = wv & 3;
  const int lr  = l & 15;
  const int lg  = (l >> 4) & 3;

  const int xcd = (int)blockIdx.x & 7;
  const int j   = (int)blockIdx.x >> 3;
  const int nbn = N >> 8;
  const int bmpx = ((int)gridDim.x >> 3) / nbn;
  const int bm = (xcd * bmpx + j / nbn) << 8;
  const int bn = (j % nbn) << 8;

  const int srw = wv * 8 + (l >> 3);
  const int sch = ((l & 7) ^ ((l >> 3) & 7)) * 8;
  const int dst = (l & 7) * 8;

  const int csw0 = (lg ^ (lr & 7)) * 8;
  const int csw1 = ((4 + lg) ^ (lr & 7)) * 8;
  const int ar = wr * 64;
  const int br = wc * 32;

  f32x4 acc[8][4];
#pragma unroll
  for (int mi = 0; mi < 8; mi++)
#pragma unroll
    for (int nj = 0; nj < 4; nj++)
      acc[mi][nj] = (f32x4){0.f, 0.f, 0.f, 0.f};

  const int NT = K >> 6;

  auto stA = [&](int h, int tt) {
#pragma unroll
    for (int L = 0; L < 2; ++L)
      gload_lds16(A + (size_t)(bm + h * 128 + L * 64 + srw) * K + tt * 64 + sch,
                  &Asl[tt & 1][h][(L * 64 + srw) * 64 + dst]);
  };
  auto stB = [&](int h, int tt) {
#pragma unroll
    for (int L = 0; L < 2; ++L)
      gload_lds16(Bt + (size_t)(bn + h * 128 + L * 64 + srw) * K + tt * 64 + sch,
                  &Bsl[tt & 1][h][(L * 64 + srw) * 64 + dst]);
  };

  stA(0, 0); stB(0, 0); stB(1, 0); stA(1, 0);
  asm volatile("s_waitcnt vmcnt(4)" ::: "memory");
  asm volatile("s_barrier" ::: "memory");

  bf16x8 af[4][2], bfr[2][2][2];

  for (int t = 0; t < NT; ++t) {
    const int cb = t & 1;
    const bool st = (t + 1 < NT);
    const u16* Ah0 = &Asl[cb][0][0];
    const u16* Ah1 = &Asl[cb][1][0];
    const u16* Bh0 = &Bsl[cb][0][0];
    const u16* Bh1 = &Bsl[cb][1][0];

    // ---- P1 ----
#pragma unroll
    for (int m = 0; m < 4; ++m) {
      af[m][0] = *reinterpret_cast<const bf16x8*>(Ah0 + (ar + m * 16 + lr) * 64 + csw0);
      af[m][1] = *reinterpret_cast<const bf16x8*>(Ah0 + (ar + m * 16 + lr) * 64 + csw1);
    }
#pragma unroll
    for (int n = 0; n < 2; ++n) {
      bfr[0][n][0] = *reinterpret_cast<const bf16x8*>(Bh0 + (br + n * 16 + lr) * 64 + csw0);
      bfr[0][n][1] = *reinterpret_cast<const bf16x8*>(Bh0 + (br + n * 16 + lr) * 64 + csw1);
    }
    if (st) { stA(0, t + 1); stB(0, t + 1); }
    asm volatile("s_barrier" ::: "memory");
    __builtin_amdgcn_s_setprio(1);
#pragma unroll
    for (int m = 0; m < 4; ++m)
#pragma unroll
      for (int n = 0; n < 2; ++n) {
        acc[m][n] = __builtin_amdgcn_mfma_f32_16x16x32_bf16(af[m][0], bfr[0][n][0], acc[m][n], 0, 0, 0);
        acc[m][n] = __builtin_amdgcn_mfma_f32_16x16x32_bf16(af[m][1], bfr[0][n][1], acc[m][n], 0, 0, 0);
      }
    __builtin_amdgcn_s_setprio(0);
    if (st) asm volatile("s_waitcnt vmcnt(6)" ::: "memory");
    else    asm volatile("s_waitcnt vmcnt(2)" ::: "memory");
    asm volatile("s_barrier" ::: "memory");

    // ---- P2 ----
#pragma unroll
    for (int n = 0; n < 2; ++n) {
      bfr[1][n][0] = *reinterpret_cast<const bf16x8*>(Bh1 + (br + n * 16 + lr) * 64 + csw0);
      bfr[1][n][1] = *reinterpret_cast<const bf16x8*>(Bh1 + (br + n * 16 + lr) * 64 + csw1);
    }
    if (st) stB(1, t + 1);
    asm volatile("s_barrier" ::: "memory");
    __builtin_amdgcn_s_setprio(1);
#pragma unroll
    for (int m = 0; m < 4; ++m)
#pragma unroll
      for (int n = 0; n < 2; ++n) {
        acc[m][2 + n] = __builtin_amdgcn_mfma_f32_16x16x32_bf16(af[m][0], bfr[1][n][0], acc[m][2 + n], 0, 0, 0);
        acc[m][2 + n] = __builtin_amdgcn_mfma_f32_16x16x32_bf16(af[m][1], bfr[1][n][1], acc[m][2 + n], 0, 0, 0);
      }
    __builtin_amdgcn_s_setprio(0);
    if (st) asm volatile("s_waitcnt vmcnt(6)" ::: "memory");
    else    asm volatile("s_waitcnt vmcnt(0)" ::: "memory");
    asm volatile("s_barrier" ::: "memory");

    // ---- P3 ----
#pragma unroll
    for (int m = 0; m < 4; ++m) {
      af[m][0] = *reinterpret_cast<const bf16x8*>(Ah1 + (ar + m * 16 + lr) * 64 + csw0);
      af[m][1] = *reinterpret_cast<const bf16x8*>(Ah1 + (ar + m * 16 + lr) * 64 + csw1);
    }
    if (st) stA(1, t + 1);
    asm volatile("s_barrier" ::: "memory");
    __builtin_amdgcn_s_setprio(1);
#pragma unroll
    for (int m = 0; m < 4; ++m)
#pragma unroll
      for (int n = 0; n < 2; ++n) {
        acc[4 + m][n] = __builtin_amdgcn_mfma_f32_16x16x32_bf16(af[m][0], bfr[0][n][0], acc[4 + m][n], 0, 0, 0);
        acc[4 + m][n] = __builtin_amdgcn_mfma_f32_16x16x32_bf16(af[m][1], bfr[0][n][1], acc[4 + m][n], 0, 0, 0);
      }
    __builtin_amdgcn_s_setprio(0);
    asm volatile("s_barrier" ::: "memory");

    // ---- P4 ----
    __builtin_amdgcn_s_setprio(1);
#pragma unroll
    for (int m = 0; m < 4; ++m)
#pragma unroll
      for (int n = 0; n < 2; ++n) {
        acc[4 + m][2 + n] = __builtin_amdgcn_mfma_f32_16x16x32_bf16(af[m][0], bfr[1][n][0], acc[4 + m][2 + n], 0, 0, 0);
        acc[4 + m][2 + n] = __builtin_amdgcn_mfma_f32_16x16x32_bf16(af[m][1], bfr[1][n][1], acc[4 + m][2 + n], 0, 0, 0);
      }
    __builtin_amdgcn_s_setprio(0);
    if (st) asm volatile("s_waitcnt vmcnt(4)" ::: "memory");
    asm volatile("s_barrier" ::: "memory");
  }

  // epilogue
#pragma unroll
  for (int mi = 0; mi < 8; ++mi) {
    const int row0 = bm + (mi >> 2) * 128 + wr * 64 + (mi & 3) * 16 + lg * 4;
#pragma unroll
    for (int nj = 0; nj < 4; ++nj) {
      const int col = bn + (nj >> 1) * 128 + wc * 32 + (nj & 1) * 16 + lr;
      const float bv = bias[col];
      u16 ov[4];
#pragma unroll
      for (int r = 0; r < 4; ++r) {
        const int row = row0 + r;
        float v = acc[mi][nj][r] + bv;
        if constexpr (EPI == EPI_BIAS_RELU_BF16) v = fmaxf(v, 0.0f);
        if constexpr (EPI == EPI_BIAS_RES_F32) {
          float* out = (float*)outp;
          out[(size_t)row * N + col] = v + res[(size_t)row * N + col];
        } else {
          ov[r] = f2bf(v);
          ((u16*)outp)[(size_t)row * N + col] = ov[r];
        }
      }
      if constexpr (FVT) {
        if (col >= 2 * Cc) {   // V columns -> vt[b][h][d][t], t = row&2047
          const int bq = row0 >> 11;
          const int t0 = row0 & 2047;
          const int hh2 = (col - 2 * Cc) >> 6;
          const int dd2 = col & 63;
          union { u16 u[4]; ushort4 v4; } pkv;
          pkv.u[0] = ov[0]; pkv.u[1] = ov[1]; pkv.u[2] = ov[2]; pkv.u[3] = ov[3];
          *reinterpret_cast<ushort4*>(
              &vtout[((size_t)(bq * Hh + hh2) * Dd + dd2) * Tt + t0]) = pkv.v4;
        }
      }
    }
  }
}

// ---------------- GEMM 128x128 (proj / FC2): m97 + T2 swizzle + L2 remap ----------------
template <int EPI>
__global__ __launch_bounds__(256, 3) void gemm_bt2(
    const u16* __restrict__ A, const u16* __restrict__ Bt,
    const float* __restrict__ bias, const float* __restrict__ res,
    void* __restrict__ outp, int M, int N, int K)
{
  constexpr int BM = 128, BN = 128, BK = 64;
  __shared__ alignas(16) u16 As[BM][BK];
  __shared__ alignas(16) u16 Bs[BN][BK];
  const int tid  = threadIdx.x;
  const int lane = tid & 63;
  const int wv   = tid >> 6;
  const int wr   = wv >> 1, wc = wv & 1;
  const int lr   = lane & 15, lg = lane >> 4;

  const int xcd = (int)blockIdx.x & 7;
  const int j   = (int)blockIdx.x >> 3;
  const int nbn = N >> 7;
  const int bmpx = ((int)gridDim.x >> 3) / nbn;
  const int bm = (xcd * bmpx + j / nbn) << 7;
  const int bn = (j % nbn) << 7;

  f32x4 acc[4][4];
#pragma unroll
  for (int mi = 0; mi < 4; mi++)
#pragma unroll
    for (int nj = 0; nj < 4; nj++)
      acc[mi][nj] = (f32x4){0.f, 0.f, 0.f, 0.f};

  const int srow = tid >> 3;
  const int scol = ((tid & 7) ^ (srow & 7)) * 8;
  const u16* ga = &A [(size_t)(bm + srow) * K + scol];
  const u16* gb = &Bt[(size_t)(bn + srow) * K + scol];
  u16* as_dst = &As[0][0] + (size_t)tid * 8;
  u16* bs_dst = &Bs[0][0] + (size_t)tid * 8;

  for (int k0 = 0; k0 < K; k0 += BK) {
#pragma unroll
    for (int p = 0; p < 4; p++) {
      gload_lds16(ga + (size_t)p * 32 * K + k0, as_dst + p * 2048);
      gload_lds16(gb + (size_t)p * 32 * K + k0, bs_dst + p * 2048);
    }
    __syncthreads();
#pragma unroll
    for (int kk = 0; kk < BK; kk += 32) {
      const int cb = kk >> 3;
      const int csw = ((cb + lg) ^ (lr & 7)) * 8;
      bf16x8 af[4], bfr[4];
#pragma unroll
      for (int mi = 0; mi < 4; mi++)
        af[mi] = *reinterpret_cast<const bf16x8*>(&As[wr * 64 + mi * 16 + lr][0] + csw);
#pragma unroll
      for (int nj = 0; nj < 4; nj++)
        bfr[nj] = *reinterpret_cast<const bf16x8*>(&Bs[wc * 64 + nj * 16 + lr][0] + csw);
#pragma unroll
      for (int mi = 0; mi < 4; mi++)
#pragma unroll
        for (int nj = 0; nj < 4; nj++)
          acc[mi][nj] = __builtin_amdgcn_mfma_f32_16x16x32_bf16(af[mi], bfr[nj], acc[mi][nj], 0, 0, 0);
    }
    __syncthreads();
  }

#pragma unroll
  for (int mi = 0; mi < 4; mi++) {
#pragma unroll
    for (int nj = 0; nj < 4; nj++) {
      const int col = bn + wc * 64 + nj * 16 + lr;
      const float bv = bias[col];
#pragma unroll
      for (int r = 0; r < 4; r++) {
        const int row = bm + wr * 64 + mi * 16 + lg * 4 + r;
        float v = acc[mi][nj][r] + bv;
        if constexpr (EPI == EPI_BIAS_RELU_BF16) v = fmaxf(v, 0.0f);
        if constexpr (EPI == EPI_BIAS_RES_F32) {
          float* out = (float*)outp;
          out[(size_t)row * N + col] = v + res[(size_t)row * N + col];
        } else {
          ((u16*)outp)[(size_t)row * N + col] = f2bf(v);
        }
      }
    }
  }
}

// ---------------- flash attention: 64 q-rows/wave, dual-chain, SIMD-paired ----------------
__global__ __launch_bounds__(512, 1) void flash_attn(
    const u16* __restrict__ qkv,   // [B][T][3C]
    const u16* __restrict__ vt,    // [B][H][D][T]
    u16* __restrict__ y)           // [B][T][C]
{
  const int tid = threadIdx.x, lane = tid & 63, wv = tid >> 6;
  const int l31 = lane & 31, hf = lane >> 5;

  const int bid = blockIdx.x;
  const int lid = (bid & 7) * 32 + (bid >> 3);
  const int bh = lid >> 2, pg = lid & 3;
  const int b = bh >> 4, h = bh & 15;
  const int sbase = pg * 4 + (wv & 3);
  const int s = (wv < 4) ? sbase : (31 - sbase);

  const u16* qbase = qkv + (size_t)b * Tt * C3 + h * Dd;
  const u16* kbase = qbase + Cc;
  const u16* vbase = vt + (size_t)bh * Dd * Tt;

  bool dmask[16];
#pragma unroll
  for (int r = 0; r < 16; r++)
    dmask[r] = ((r & 3) + 8 * (r >> 2) + 4 * hf) > l31;

  const int qa0 = s * 64;
  const int qb0 = qa0 + 32;
  const int ta = 2 * s;

  bf16x8 qfa[4], qfb[4];
#pragma unroll
  for (int kc = 0; kc < 4; kc++) {
    qfa[kc] = *reinterpret_cast<const bf16x8*>(
        &qbase[(size_t)(qa0 + l31) * C3 + kc * 16 + hf * 8]);
    qfb[kc] = *reinterpret_cast<const bf16x8*>(
        &qbase[(size_t)(qb0 + l31) * C3 + kc * 16 + hf * 8]);
  }

  f32x16 oa[2], ob[2];
#pragma unroll
  for (int i = 0; i < 16; i++) { oa[0][i] = 0.f; oa[1][i] = 0.f; ob[0][i] = 0.f; ob[1][i] = 0.f; }
  float mA = -INFINITY, lA = 0.0f, mB = -INFINITY, lB = 0.0f;

  const u16* kptr = &kbase[(size_t)l31 * C3 + hf * 8];
  const u16* vp0 = &vbase[(size_t)l31 * Tt + hf * 8];
  const u16* vp1 = vp0 + (size_t)32 * Tt;

  bf16x8 kf[4];
#pragma unroll
  for (int kc = 0; kc < 4; kc++)
    kf[kc] = *reinterpret_cast<const bf16x8*>(kptr + kc * 16);

  for (int kt = 0; kt <= ta; ++kt) {
    bf16x8 vf[2][2];
#pragma unroll
    for (int ch = 0; ch < 2; ch++) {
      vf[0][ch] = *reinterpret_cast<const bf16x8*>(vp0 + ch * 16);
      vf[1][ch] = *reinterpret_cast<const bf16x8*>(vp1 + ch * 16);
    }
    vp0 += 32; vp1 += 32;

    f32x16 sA, sB;
#pragma unroll
    for (int i = 0; i < 16; i++) { sA[i] = 0.f; sB[i] = 0.f; }
#pragma unroll
    for (int kc = 0; kc < 4; kc++) {
      sA = __builtin_amdgcn_mfma_f32_32x32x16_bf16(kf[kc], qfa[kc], sA, 0, 0, 0);
      sB = __builtin_amdgcn_mfma_f32_32x32x16_bf16(kf[kc], qfb[kc], sB, 0, 0, 0);
    }

    kptr += (size_t)32 * C3;
    bf16x8 kn[4];
#pragma unroll
    for (int kc = 0; kc < 4; kc++)
      kn[kc] = *reinterpret_cast<const bf16x8*>(kptr + kc * 16);

    const bool diagA = (kt == ta);

    float svA[16], svB[16];
#pragma unroll
    for (int r = 0; r < 16; r++) {
      svA[r] = sA[r];
      if (diagA && dmask[r]) svA[r] = -INFINITY;
      svB[r] = sB[r];
    }

    float mAa = fmaxf(fmaxf(svA[0], svA[1]), fmaxf(svA[2], svA[3]));
    float mAb = fmaxf(fmaxf(svA[4], svA[5]), fmaxf(svA[6], svA[7]));
    float mAc = fmaxf(fmaxf(svA[8], svA[9]), fmaxf(svA[10], svA[11]));
    float mAd = fmaxf(fmaxf(svA[12], svA[13]), fmaxf(svA[14], svA[15]));
    float m8A = fmaxf(fmaxf(mAa, mAb), fmaxf(mAc, mAd));
    float mBa = fmaxf(fmaxf(svB[0], svB[1]), fmaxf(svB[2], svB[3]));
    float mBb = fmaxf(fmaxf(svB[4], svB[5]), fmaxf(svB[6], svB[7]));
    float mBc = fmaxf(fmaxf(svB[8], svB[9]), fmaxf(svB[10], svB[11]));
    float mBd = fmaxf(fmaxf(svB[12], svB[13]), fmaxf(svB[14], svB[15]));
    float m8B = fmaxf(fmaxf(mBa, mBb), fmaxf(mBc, mBd));
    m8A = xhalf_max(m8A);
    m8B = xhalf_max(m8B);

    if (!__all(m8A - mA <= 64.0f)) {
      const float mnew  = fmaxf(mA, m8A);
      const float alpha = exp2_hw((mA - mnew) * SCL2);
      lA *= alpha;
#pragma unroll
      for (int i = 0; i < 16; i++) { oa[0][i] *= alpha; oa[1][i] *= alpha; }
      mA = mnew;
    }
    if (!__all(m8B - mB <= 64.0f)) {
      const float mnew  = fmaxf(mB, m8B);
      const float alpha = exp2_hw((mB - mnew) * SCL2);
      lB *= alpha;
#pragma unroll
      for (int i = 0; i < 16; i++) { ob[0][i] *= alpha; ob[1][i] *= alpha; }
      mB = mnew;
    }

    const float msA = mA * SCL2;
    const float msB = mB * SCL2;
    float pA[16], pB[16];
#pragma unroll
    for (int r = 0; r < 16; r++) {
      pA[r] = exp2_hw(fmaf(svA[r], SCL2, -msA));
      pB[r] = exp2_hw(fmaf(svB[r], SCL2, -msB));
    }
    {
      float a0 = ((pA[0] + pA[1]) + (pA[2] + pA[3])) + ((pA[4] + pA[5]) + (pA[6] + pA[7]));
      float a1 = ((pA[8] + pA[9]) + (pA[10] + pA[11])) + ((pA[12] + pA[13]) + (pA[14] + pA[15]));
      lA += a0 + a1;
      float b0 = ((pB[0] + pB[1]) + (pB[2] + pB[3])) + ((pB[4] + pB[5]) + (pB[6] + pB[7]));
      float b1 = ((pB[8] + pB[9]) + (pB[10] + pB[11])) + ((pB[12] + pB[13]) + (pB[14] + pB[15]));
      lB += b0 + b1;
    }

    unsigned pwA[2][4], pwB[2][4];
#pragma unroll
    for (int ch = 0; ch < 2; ch++) {
      const int bs = ch * 8;
      {
        unsigned w0 = pk2(pA[bs + 0], pA[bs + 1]);
        unsigned w1 = pk2(pA[bs + 2], pA[bs + 3]);
        unsigned w2 = pk2(pA[bs + 4], pA[bs + 5]);
        unsigned w3 = pk2(pA[bs + 6], pA[bs + 7]);
        uint2v r02 = plswap(w0, w2);
        uint2v r13 = plswap(w1, w3);
        pwA[ch][0] = r02[0]; pwA[ch][2] = r02[1];
        pwA[ch][1] = r13[0]; pwA[ch][3] = r13[1];
      }
      {
        unsigned w0 = pk2(pB[bs + 0], pB[bs + 1]);
        unsigned w1 = pk2(pB[bs + 2], pB[bs + 3]);
        unsigned w2 = pk2(pB[bs + 4], pB[bs + 5]);
        unsigned w3 = pk2(pB[bs + 6], pB[bs + 7]);
        uint2v r02 = plswap(w0, w2);
        uint2v r13 = plswap(w1, w3);
        pwB[ch][0] = r02[0]; pwB[ch][2] = r02[1];
        pwB[ch][1] = r13[0]; pwB[ch][3] = r13[1];
      }
    }

#pragma unroll
    for (int d0i = 0; d0i < 2; d0i++)
#pragma unroll
      for (int ch = 0; ch < 2; ch++) {
        union { unsigned w[4]; bf16x8 v; } pa, pb;
        pa.w[0] = pwA[ch][0]; pa.w[1] = pwA[ch][1];
        pa.w[2] = pwA[ch][2]; pa.w[3] = pwA[ch][3];
        pb.w[0] = pwB[ch][0]; pb.w[1] = pwB[ch][1];
        pb.w[2] = pwB[ch][2]; pb.w[3] = pwB[ch][3];
        oa[d0i] = __builtin_amdgcn_mfma_f32_32x32x16_bf16(vf[d0i][ch], pa.v, oa[d0i], 0, 0, 0);
        ob[d0i] = __builtin_amdgcn_mfma_f32_32x32x16_bf16(vf[d0i][ch], pb.v, ob[d0i], 0, 0, 0);
      }

#pragma unroll
    for (int kc = 0; kc < 4; kc++) kf[kc] = kn[kc];
  }

  // peeled tile: group B only, diagonal-masked
  {
    bf16x8 vf[2][2];
#pragma unroll
    for (int ch = 0; ch < 2; ch++) {
      vf[0][ch] = *reinterpret_cast<const bf16x8*>(vp0 + ch * 16);
      vf[1][ch] = *reinterpret_cast<const bf16x8*>(vp1 + ch * 16);
    }

    f32x16 sB;
#pragma unroll
    for (int i = 0; i < 16; i++) sB[i] = 0.f;
#pragma unroll
    for (int kc = 0; kc < 4; kc++)
      sB = __builtin_amdgcn_mfma_f32_32x32x16_bf16(kf[kc], qfb[kc], sB, 0, 0, 0);

    float svB[16];
#pragma unroll
    for (int r = 0; r < 16; r++) {
      svB[r] = sB[r];
      if (dmask[r]) svB[r] = -INFINITY;
    }
    float mBa = fmaxf(fmaxf(svB[0], svB[1]), fmaxf(svB[2], svB[3]));
    float mBb = fmaxf(fmaxf(svB[4], svB[5]), fmaxf(svB[6], svB[7]));
    float mBc = fmaxf(fmaxf(svB[8], svB[9]), fmaxf(svB[10], svB[11]));
    float mBd = fmaxf(fmaxf(svB[12], svB[13]), fmaxf(svB[14], svB[15]));
    float m8B = fmaxf(fmaxf(mBa, mBb), fmaxf(mBc, mBd));
    m8B = xhalf_max(m8B);

    if (!__all(m8B - mB <= 64.0f)) {
      const float mnew  = fmaxf(mB, m8B);
      const float alpha = exp2_hw((mB - mnew) * SCL2);
      lB *= alpha;
#pragma unroll
      for (int i = 0; i < 16; i++) { ob[0][i] *= alpha; ob[1][i] *= alpha; }
      mB = mnew;
    }
    const float msB = mB * SCL2;
    float pB[16];
#pragma unroll
    for (int r = 0; r < 16; r++)
      pB[r] = exp2_hw(fmaf(svB[r], SCL2, -msB));
    {
      float b0 = ((pB[0] + pB[1]) + (pB[2] + pB[3])) + ((pB[4] + pB[5]) + (pB[6] + pB[7]));
      float b1 = ((pB[8] + pB[9]) + (pB[10] + pB[11])) + ((pB[12] + pB[13]) + (pB[14] + pB[15]));
      lB += b0 + b1;
    }
    unsigned pwB[2][4];
#pragma unroll
    for (int ch = 0; ch < 2; ch++) {
      const int bs = ch * 8;
      unsigned w0 = pk2(pB[bs + 0], pB[bs + 1]);
      unsigned w1 = pk2(pB[bs + 2], pB[bs + 3]);
      unsigned w2 = pk2(pB[bs + 4], pB[bs + 5]);
      unsigned w3 = pk2(pB[bs + 6], pB[bs + 7]);
      uint2v r02 = plswap(w0, w2);
      uint2v r13 = plswap(w1, w3);
      pwB[ch][0] = r02[0]; pwB[ch][2] = r02[1];
      pwB[ch][1] = r13[0]; pwB[ch][3] = r13[1];
    }
#pragma unroll
    for (int d0i = 0; d0i < 2; d0i++)
#pragma unroll
      for (int ch = 0; ch < 2; ch++) {
        union { unsigned w[4]; bf16x8 v; } pb;
        pb.w[0] = pwB[ch][0]; pb.w[1] = pwB[ch][1];
        pb.w[2] = pwB[ch][2]; pb.w[3] = pwB[ch][3];
        ob[d0i] = __builtin_amdgcn_mfma_f32_32x32x16_bf16(vf[d0i][ch], pb.v, ob[d0i], 0, 0, 0);
      }
  }

  {
    const float lsA = xhalf_sum(lA);
    const float invA = 1.0f / lsA;
    u16* yrow = y + (size_t)(b * Tt + qa0 + l31) * Cc + h * Dd;
#pragma unroll
    for (int d0i = 0; d0i < 2; d0i++)
#pragma unroll
      for (int qd = 0; qd < 4; qd++) {
        ushort4 o;
        o.x = bfn(oa[d0i][qd * 4 + 0] * invA);
        o.y = bfn(oa[d0i][qd * 4 + 1] * invA);
        o.z = bfn(oa[d0i][qd * 4 + 2] * invA);
        o.w = bfn(oa[d0i][qd * 4 + 3] * invA);
        *reinterpret_cast<ushort4*>(&yrow[d0i * 32 + qd * 8 + hf * 4]) = o;
      }
  }
  {
    const float lsB = xhalf_sum(lB);
    const float invB = 1.0f / lsB;
    u16* yrow = y + (size_t)(b * Tt + qb0 + l31) * Cc + h * Dd;
#pragma unroll
    for (int d0i = 0; d0i < 2; d0i++)
#pragma unroll
      for (int qd = 0; qd < 4; qd++) {
        ushort4 o;
        o.x = bfn(ob[d0i][qd * 4 + 0] * invB);
        o.y = bfn(ob[d0i][qd * 4 + 1] * invB);
        o.z = bfn(ob[d0i][qd * 4 + 2] * invB);
        o.w = bfn(ob[d0i][qd * 4 + 3] * invB);
        *reinterpret_cast<ushort4*>(&yrow[d0i * 32 + qd * 8 + hf * 4]) = o;
      }
  }
}

// ---------------- launch ----------------
extern "C" void kernel_launch(void* const* d_in, const int* in_sizes, int n_in,
                              void* d_out, int out_size, void* d_ws, size_t ws_size,
                              hipStream_t stream)
{
  const float* x      = (const float*)d_in[0];
  const float* ln1_g  = (const float*)d_in[1];
  const float* ln1_b  = (const float*)d_in[2];
  const float* attn_w = (const float*)d_in[3];
  const float* attn_b = (const float*)d_in[4];
  const float* proj_w = (const float*)d_in[5];
  const float* proj_b = (const float*)d_in[6];
  const float* ln2_g  = (const float*)d_in[7];
  const float* ln2_b  = (const float*)d_in[8];
  const float* fc1_w  = (const float*)d_in[9];
  const float* fc1_b  = (const float*)d_in[10];
  const float* fc2_w  = (const float*)d_in[11];
  const float* fc2_b  = (const float*)d_in[12];
  float* out = (float*)d_out;

  char* ws = (char*)d_ws;
  size_t o = 0;
  auto alloc = [&](size_t bytes) { char* p = ws + o; o += bytes; return p; };
  u16* wqkv_t  = (u16*)alloc((size_t)C3 * Cc * 2);
  u16* wproj_t = (u16*)alloc((size_t)Cc * Cc * 2);
  u16* wfc1_t  = (u16*)alloc((size_t)4096 * Cc * 2);
  u16* wfc2_t  = (u16*)alloc((size_t)Cc * 4096 * 2);
  u16* h_bf    = (u16*)alloc((size_t)ROWS * Cc * 2);
  u16* y_bf    = (u16*)alloc((size_t)ROWS * Cc * 2);
  u16* qkv_raw = (u16*)alloc((size_t)ROWS * C3 * 2);
  u16* vt      = (u16*)alloc((size_t)Bb * Hh * Dd * Tt * 2);
  u16* hh      = qkv_raw; // aliases qkv_raw+vt, both dead by FC1 time

  wcast_all<<<12288, 256, 0, stream>>>(attn_w, wqkv_t, proj_w, wproj_t,
                                       fc1_w, wfc1_t, fc2_w, wfc2_t);

  ln_kernel<<<ROWS / 4, 256, 0, stream>>>(x, ln1_g, ln1_b, h_bf);
  gemm8p<EPI_BIAS_BF16, true><<<8 * (ROWS / 256 / 8) * (C3 / 256), 512, 0, stream>>>(
      h_bf, wqkv_t, attn_b, nullptr, qkv_raw, vt, ROWS, C3, Cc);
  flash_attn<<<dim3(256), 512, 0, stream>>>(qkv_raw, vt, y_bf);
  gemm_bt2<EPI_BIAS_RES_F32><<<64 * (Cc / 128), 256, 0, stream>>>(
      y_bf, wproj_t, proj_b, x, out, ROWS, Cc, Cc);
  ln_kernel<<<ROWS / 4, 256, 0, stream>>>(out, ln2_g, ln2_b, h_bf);
  gemm8p<EPI_BIAS_RELU_BF16, false><<<8 * (ROWS / 256 / 8) * (4096 / 256), 512, 0, stream>>>(
      h_bf, wfc1_t, fc1_b, nullptr, hh, nullptr, ROWS, 4096, Cc);
  gemm_bt2<EPI_BIAS_RES_F32><<<64 * (Cc / 128), 256, 0, stream>>>(
      hh, wfc2_t, fc2_b, out, out, ROWS, Cc, 4096);
}